// Round 1
// baseline (841.100 us; speedup 1.0000x reference)
//
#include <hip/hip_runtime.h>
#include <hip/hip_bf16.h>
#include <math.h>

typedef __bf16 bf16;
typedef __bf16 bf16x4 __attribute__((ext_vector_type(4)));
typedef __bf16 bf16x8 __attribute__((ext_vector_type(8)));
typedef float f32x4 __attribute__((ext_vector_type(4)));

#define DEV static __device__ __forceinline__

constexpr int Dm = 1024;   // model dim
constexpr int Hh = 16;     // heads
constexpr int Sq = 2048;   // seq len
constexpr int Mrows = 4096; // B*S
constexpr size_t AE = (size_t)Mrows * Dm; // elems per activation array (4194304)

DEV void gload_lds16(const void* g, void* l) {
  __builtin_amdgcn_global_load_lds((const __attribute__((address_space(1))) unsigned int*)g,
                                   (__attribute__((address_space(3))) unsigned int*)l,
                                   16, 0, 0);
}

DEV float gelu_f(float u) {
  const float c = 0.7978845608028654f; // sqrt(2/pi)
  float t = tanhf(c * (u + 0.044715f * u * u * u));
  return 0.5f * u * (1.0f + t);
}

// ---------------- weight transpose + hi/lo split: W[K][N] -> T[N][K] ----------------
__global__ void transpose_split_kernel(const float* __restrict__ W,
                                       bf16* __restrict__ Thi, bf16* __restrict__ Tlo,
                                       int K, int N) {
  __shared__ float tile[64][65];
  const int t = threadIdx.x;
  const int nt = blockIdx.x * 64, kt = blockIdx.y * 64;
  #pragma unroll
  for (int i = 0; i < 16; ++i) {
    int id = i * 256 + t;
    int r = id >> 6, c = id & 63;
    tile[r][c] = W[(size_t)(kt + r) * N + nt + c];
  }
  __syncthreads();
  #pragma unroll
  for (int i = 0; i < 16; ++i) {
    int id = i * 256 + t;
    int n = id >> 6, k = id & 63;
    float v = tile[k][n];
    bf16 hi = (bf16)v;
    size_t ad = (size_t)(nt + n) * K + kt + k;
    Thi[ad] = hi;
    Tlo[ad] = (bf16)(v - (float)hi);
  }
}

// ---------------- LayerNorm + hi/lo split (one block per row of 1024) ----------------
__global__ void ln_split_kernel(const float* __restrict__ x,
                                const float* __restrict__ gamma, const float* __restrict__ beta,
                                bf16* __restrict__ ohi, bf16* __restrict__ olo) {
  const int row = blockIdx.x, t = threadIdx.x;
  const float4 v = ((const float4*)(x + (size_t)row * Dm))[t];
  float s = v.x + v.y + v.z + v.w;
  float sq = v.x * v.x + v.y * v.y + v.z * v.z + v.w * v.w;
  #pragma unroll
  for (int off = 1; off < 64; off <<= 1) {
    s += __shfl_xor(s, off);
    sq += __shfl_xor(sq, off);
  }
  __shared__ float red[8];
  const int wave = t >> 6, lane = t & 63;
  if (lane == 0) { red[wave] = s; red[4 + wave] = sq; }
  __syncthreads();
  s = red[0] + red[1] + red[2] + red[3];
  sq = red[4] + red[5] + red[6] + red[7];
  const float mean = s * (1.0f / 1024.0f);
  const float var = sq * (1.0f / 1024.0f) - mean * mean;
  const float inv = 1.0f / sqrtf(var + 1e-5f);
  const float4 g4 = ((const float4*)gamma)[t];
  const float4 b4 = ((const float4*)beta)[t];
  float y[4];
  y[0] = (v.x - mean) * inv * g4.x + b4.x;
  y[1] = (v.y - mean) * inv * g4.y + b4.y;
  y[2] = (v.z - mean) * inv * g4.z + b4.z;
  y[3] = (v.w - mean) * inv * g4.w + b4.w;
  bf16x4 hv, lv;
  #pragma unroll
  for (int i = 0; i < 4; ++i) {
    bf16 hi = (bf16)y[i];
    hv[i] = hi;
    lv[i] = (bf16)(y[i] - (float)hi);
  }
  ((bf16x4*)(ohi + (size_t)row * Dm))[t] = hv;
  ((bf16x4*)(olo + (size_t)row * Dm))[t] = lv;
}

// ---------------- split-bf16 GEMM: C = (Ahi+Alo) @ (Bhi+Blo)^T(stored [N][K]) ----------------
// 3 K-segments: hi*hi, lo*hi, hi*lo. Tile BM x 128, 4 waves (2x2), BK=64.
// EP: 0 = QKV (write q/k natural + v transposed, hi/lo), 1 = bias+residual fp32, 2 = gelu+split.
template<int BM, int EP>
__global__ __launch_bounds__(256, 2) void gemm_kernel(
    const bf16* __restrict__ Ahi, const bf16* __restrict__ Alo,
    const bf16* __restrict__ Bthi, const bf16* __restrict__ Btlo,
    int K, int N,
    bf16* __restrict__ Ohi, bf16* __restrict__ Olo,
    float* __restrict__ Of,
    const float* __restrict__ bias, const float* __restrict__ resid) {
  constexpr int FM = BM / 32;  // M-frags per wave
  constexpr int FN = 4;        // N-frags per wave (wave tile = BM/2 x 64)
  const int t = threadIdx.x, wave = t >> 6, lane = t & 63;
  const int wr = wave >> 1, wc = wave & 1;
  const int l15 = lane & 15, l4 = lane >> 4;
  const int row0 = blockIdx.y * BM, col0 = blockIdx.x * 128;

  __shared__ __align__(16) bf16 sA[BM * 64];
  __shared__ __align__(16) bf16 sB[128 * 64];

  f32x4 acc[FM][FN];
  #pragma unroll
  for (int m = 0; m < FM; ++m)
    #pragma unroll
    for (int n = 0; n < FN; ++n)
      acc[m][n] = (f32x4){0.f, 0.f, 0.f, 0.f};

  for (int seg = 0; seg < 3; ++seg) {
    const bf16* Asrc = (seg == 1) ? Alo : Ahi;
    const bf16* Bsrc = (seg == 2) ? Btlo : Bthi;
    for (int kt = 0; kt < K; kt += 64) {
      // stage A tile [BM][64] (global chunk pre-swizzled so LDS stays linear)
      #pragma unroll
      for (int p = 0; p < BM / 32; ++p) {
        int id = p * 256 + t;
        int r = id >> 3, c = id & 7;
        const bf16* src = Asrc + (size_t)(row0 + r) * K + kt + ((c ^ (r & 7)) << 3);
        gload_lds16(src, (char*)sA + (p * 256 + wave * 64) * 16);
      }
      // stage B tile [128][64]
      #pragma unroll
      for (int p = 0; p < 4; ++p) {
        int id = p * 256 + t;
        int r = id >> 3, c = id & 7;
        const bf16* src = Bsrc + (size_t)(col0 + r) * K + kt + ((c ^ (r & 7)) << 3);
        gload_lds16(src, (char*)sB + (p * 256 + wave * 64) * 16);
      }
      __syncthreads();
      bf16x8 af[FM][2], bfr[FN][2];
      #pragma unroll
      for (int m = 0; m < FM; ++m)
        #pragma unroll
        for (int ks = 0; ks < 2; ++ks) {
          int r = wr * (BM / 2) + m * 16 + l15;
          int ch = ((ks * 4 + l4) ^ (r & 7)) << 3;
          af[m][ks] = *(const bf16x8*)&sA[r * 64 + ch];
        }
      #pragma unroll
      for (int n = 0; n < FN; ++n)
        #pragma unroll
        for (int ks = 0; ks < 2; ++ks) {
          int r = wc * 64 + n * 16 + l15;
          int ch = ((ks * 4 + l4) ^ (r & 7)) << 3;
          bfr[n][ks] = *(const bf16x8*)&sB[r * 64 + ch];
        }
      #pragma unroll
      for (int ks = 0; ks < 2; ++ks)
        #pragma unroll
        for (int m = 0; m < FM; ++m)
          #pragma unroll
          for (int n = 0; n < FN; ++n)
            acc[m][n] = __builtin_amdgcn_mfma_f32_16x16x32_bf16(af[m][ks], bfr[n][ks], acc[m][n], 0, 0, 0);
      __syncthreads();
    }
  }

  // epilogue
  #pragma unroll
  for (int m = 0; m < FM; ++m)
    #pragma unroll
    for (int n = 0; n < FN; ++n)
      #pragma unroll
      for (int rr = 0; rr < 4; ++rr) {
        int row = row0 + wr * (BM / 2) + m * 16 + l4 * 4 + rr;
        int col = col0 + wc * 64 + n * 16 + l15;
        float v = acc[m][n][rr];
        if constexpr (EP == 0) {
          int which = col >> 10;
          int c = col & 1023;
          bf16 hi = (bf16)v;
          bf16 lo = (bf16)(v - (float)hi);
          if (which == 0) {
            size_t ad = (size_t)row * Dm + c;
            Ohi[ad] = hi; Ohi[AE + ad] = lo;               // q hi/lo
          } else if (which == 1) {
            size_t ad = (size_t)row * Dm + c;
            Ohi[2 * AE + ad] = hi; Ohi[3 * AE + ad] = lo;  // k hi/lo
          } else {
            size_t ad = ((size_t)(row >> 11) * Dm + c) * Sq + (row & (Sq - 1));
            Ohi[4 * AE + ad] = hi; Ohi[5 * AE + ad] = lo;  // v transposed [b][h*64+hd][s]
          }
        } else if constexpr (EP == 1) {
          size_t ad = (size_t)row * N + col;
          Of[ad] = v + bias[col] + resid[ad];
        } else {
          float u = gelu_f(v + bias[col]);
          bf16 hi = (bf16)u;
          size_t ad = (size_t)row * N + col;
          Ohi[ad] = hi;
          Olo[ad] = (bf16)(u - (float)hi);
        }
      }
}

// ---------------- causal flash attention, split-bf16 MFMA ----------------
// grid: (S/128, B*H). 4 waves, each wave: 32 q-rows x 64 d. KV-block 64.
__global__ __launch_bounds__(256, 2) void attn_kernel(
    const bf16* __restrict__ qhi, const bf16* __restrict__ qlo,
    const bf16* __restrict__ khi, const bf16* __restrict__ klo,
    const bf16* __restrict__ vthi, const bf16* __restrict__ vtlo,
    bf16* __restrict__ chi, bf16* __restrict__ clo) {
  const int t = threadIdx.x, wave = t >> 6, lane = t & 63;
  const int l15 = lane & 15, l4 = lane >> 4;
  const int qt = blockIdx.x, bh = blockIdx.y;
  const int b = bh >> 4, h = bh & 15;
  const int qb = qt * 128;
  const int q0 = qb + wave * 32;

  __shared__ __align__(16) bf16 sKh[64 * 64], sKl[64 * 64], sVh[64 * 64], sVl[64 * 64];
  __shared__ __align__(16) bf16 sPh[128 * 64], sPl[128 * 64];

  // hoist Q fragments (hi and lo)
  bf16x8 qfh[2][2], qfl[2][2];
  #pragma unroll
  for (int mq = 0; mq < 2; ++mq)
    #pragma unroll
    for (int ks = 0; ks < 2; ++ks) {
      int qr = q0 + mq * 16 + l15;
      size_t ad = (size_t)(b * Sq + qr) * Dm + h * 64 + ks * 32 + l4 * 8;
      qfh[mq][ks] = *(const bf16x8*)&qhi[ad];
      qfl[mq][ks] = *(const bf16x8*)&qlo[ad];
    }

  f32x4 cacc[2][4];
  float mrun[2][4], lrun[2][4];
  #pragma unroll
  for (int mq = 0; mq < 2; ++mq) {
    #pragma unroll
    for (int nd = 0; nd < 4; ++nd) cacc[mq][nd] = (f32x4){0.f, 0.f, 0.f, 0.f};
    #pragma unroll
    for (int rr = 0; rr < 4; ++rr) { mrun[mq][rr] = -1e30f; lrun[mq][rr] = 0.f; }
  }

  const int kmax = qb + 128;
  for (int kb = 0; kb < kmax; kb += 64) {
    // stage K hi/lo [64 s][64 d] and V^T hi/lo [64 d][64 s]
    #pragma unroll
    for (int p = 0; p < 2; ++p) {
      int id = p * 256 + t;
      int r = id >> 3, c = id & 7;
      int cc = (c ^ (r & 7)) << 3;
      size_t ka = (size_t)(b * Sq + kb + r) * Dm + h * 64 + cc;
      size_t va = (size_t)(b * Dm + h * 64 + r) * Sq + kb + cc;
      char* dst = (char*)nullptr;
      (void)dst;
      gload_lds16(&khi[ka], (char*)sKh + (p * 256 + wave * 64) * 16);
      gload_lds16(&klo[ka], (char*)sKl + (p * 256 + wave * 64) * 16);
      gload_lds16(&vthi[va], (char*)sVh + (p * 256 + wave * 64) * 16);
      gload_lds16(&vtlo[va], (char*)sVl + (p * 256 + wave * 64) * 16);
    }
    __syncthreads();

    if (kb <= q0 + 31) {
      // ---------- S = Q K^T (3 split segments) ----------
      f32x4 sacc[2][4];
      #pragma unroll
      for (int mq = 0; mq < 2; ++mq)
        #pragma unroll
        for (int nk = 0; nk < 4; ++nk) sacc[mq][nk] = (f32x4){0.f, 0.f, 0.f, 0.f};
      {
        bf16x8 kf[4][2];
        #pragma unroll
        for (int nk = 0; nk < 4; ++nk)
          #pragma unroll
          for (int ks = 0; ks < 2; ++ks) {
            int r = nk * 16 + l15;
            int ch = ((ks * 4 + l4) ^ (r & 7)) << 3;
            kf[nk][ks] = *(const bf16x8*)&sKh[r * 64 + ch];
          }
        #pragma unroll
        for (int ks = 0; ks < 2; ++ks)
          #pragma unroll
          for (int mq = 0; mq < 2; ++mq)
            #pragma unroll
            for (int nk = 0; nk < 4; ++nk)
              sacc[mq][nk] = __builtin_amdgcn_mfma_f32_16x16x32_bf16(qfh[mq][ks], kf[nk][ks], sacc[mq][nk], 0, 0, 0);
        #pragma unroll
        for (int ks = 0; ks < 2; ++ks)
          #pragma unroll
          for (int mq = 0; mq < 2; ++mq)
            #pragma unroll
            for (int nk = 0; nk < 4; ++nk)
              sacc[mq][nk] = __builtin_amdgcn_mfma_f32_16x16x32_bf16(qfl[mq][ks], kf[nk][ks], sacc[mq][nk], 0, 0, 0);
        #pragma unroll
        for (int nk = 0; nk < 4; ++nk)
          #pragma unroll
          for (int ks = 0; ks < 2; ++ks) {
            int r = nk * 16 + l15;
            int ch = ((ks * 4 + l4) ^ (r & 7)) << 3;
            kf[nk][ks] = *(const bf16x8*)&sKl[r * 64 + ch];
          }
        #pragma unroll
        for (int ks = 0; ks < 2; ++ks)
          #pragma unroll
          for (int mq = 0; mq < 2; ++mq)
            #pragma unroll
            for (int nk = 0; nk < 4; ++nk)
              sacc[mq][nk] = __builtin_amdgcn_mfma_f32_16x16x32_bf16(qfh[mq][ks], kf[nk][ks], sacc[mq][nk], 0, 0, 0);
      }
      // ---------- scale, causal mask, online softmax ----------
      #pragma unroll
      for (int mq = 0; mq < 2; ++mq)
        #pragma unroll
        for (int rr = 0; rr < 4; ++rr) {
          int qr = q0 + mq * 16 + l4 * 4 + rr;
          float mx = -3e38f;
          #pragma unroll
          for (int nk = 0; nk < 4; ++nk) {
            int kp = kb + nk * 16 + l15;
            float sv = sacc[mq][nk][rr] * 0.125f;
            sv = (kp <= qr) ? sv : -1e30f;
            sacc[mq][nk][rr] = sv;
            mx = fmaxf(mx, sv);
          }
          mx = fmaxf(mx, __shfl_xor(mx, 1));
          mx = fmaxf(mx, __shfl_xor(mx, 2));
          mx = fmaxf(mx, __shfl_xor(mx, 4));
          mx = fmaxf(mx, __shfl_xor(mx, 8));
          float mold = mrun[mq][rr];
          float mnew = fmaxf(mold, mx);
          float corr = expf(mold - mnew);
          float rs = 0.f;
          #pragma unroll
          for (int nk = 0; nk < 4; ++nk) {
            float p = expf(sacc[mq][nk][rr] - mnew);
            sacc[mq][nk][rr] = p;
            rs += p;
          }
          rs += __shfl_xor(rs, 1);
          rs += __shfl_xor(rs, 2);
          rs += __shfl_xor(rs, 4);
          rs += __shfl_xor(rs, 8);
          lrun[mq][rr] = lrun[mq][rr] * corr + rs;
          mrun[mq][rr] = mnew;
          #pragma unroll
          for (int nd = 0; nd < 4; ++nd) cacc[mq][nd][rr] *= corr;
        }
      // ---------- write P (hi/lo) to swizzled LDS ----------
      #pragma unroll
      for (int mq = 0; mq < 2; ++mq)
        #pragma unroll
        for (int nk = 0; nk < 4; ++nk)
          #pragma unroll
          for (int rr = 0; rr < 4; ++rr) {
            int ql_ = wave * 32 + mq * 16 + l4 * 4 + rr;
            int kl_ = nk * 16 + l15;
            int ad = ql_ * 64 + (((kl_ >> 3) ^ (ql_ & 7)) << 3) + (kl_ & 7);
            float p = sacc[mq][nk][rr];
            bf16 ph = (bf16)p;
            sPh[ad] = ph;
            sPl[ad] = (bf16)(p - (float)ph);
          }
      // ---------- ctx += P V (3 split segments) ----------
      {
        bf16x8 pfh[2][2], pfl[2][2];
        #pragma unroll
        for (int mq = 0; mq < 2; ++mq)
          #pragma unroll
          for (int ks = 0; ks < 2; ++ks) {
            int qr_ = wave * 32 + mq * 16 + l15;
            int ch = ((ks * 4 + l4) ^ (qr_ & 7)) << 3;
            pfh[mq][ks] = *(const bf16x8*)&sPh[qr_ * 64 + ch];
            pfl[mq][ks] = *(const bf16x8*)&sPl[qr_ * 64 + ch];
          }
        bf16x8 vf[2][4];
        #pragma unroll
        for (int ks = 0; ks < 2; ++ks)
          #pragma unroll
          for (int nd = 0; nd < 4; ++nd) {
            int dr = nd * 16 + l15;
            int ch = ((ks * 4 + l4) ^ (dr & 7)) << 3;
            vf[ks][nd] = *(const bf16x8*)&sVh[dr * 64 + ch];
          }
        #pragma unroll
        for (int ks = 0; ks < 2; ++ks)
          #pragma unroll
          for (int mq = 0; mq < 2; ++mq)
            #pragma unroll
            for (int nd = 0; nd < 4; ++nd)
              cacc[mq][nd] = __builtin_amdgcn_mfma_f32_16x16x32_bf16(pfh[mq][ks], vf[ks][nd], cacc[mq][nd], 0, 0, 0);
        #pragma unroll
        for (int ks = 0; ks < 2; ++ks)
          #pragma unroll
          for (int mq = 0; mq < 2; ++mq)
            #pragma unroll
            for (int nd = 0; nd < 4; ++nd)
              cacc[mq][nd] = __builtin_amdgcn_mfma_f32_16x16x32_bf16(pfl[mq][ks], vf[ks][nd], cacc[mq][nd], 0, 0, 0);
        #pragma unroll
        for (int ks = 0; ks < 2; ++ks)
          #pragma unroll
          for (int nd = 0; nd < 4; ++nd) {
            int dr = nd * 16 + l15;
            int ch = ((ks * 4 + l4) ^ (dr & 7)) << 3;
            vf[ks][nd] = *(const bf16x8*)&sVl[dr * 64 + ch];
          }
        #pragma unroll
        for (int ks = 0; ks < 2; ++ks)
          #pragma unroll
          for (int mq = 0; mq < 2; ++mq)
            #pragma unroll
            for (int nd = 0; nd < 4; ++nd)
              cacc[mq][nd] = __builtin_amdgcn_mfma_f32_16x16x32_bf16(pfh[mq][ks], vf[ks][nd], cacc[mq][nd], 0, 0, 0);
      }
    }
    __syncthreads();
  }

  // epilogue: ctx / l, split, store natural layout
  #pragma unroll
  for (int mq = 0; mq < 2; ++mq)
    #pragma unroll
    for (int nd = 0; nd < 4; ++nd)
      #pragma unroll
      for (int rr = 0; rr < 4; ++rr) {
        int qr = q0 + mq * 16 + l4 * 4 + rr;
        float ov = cacc[mq][nd][rr] / lrun[mq][rr];
        size_t ad = (size_t)(b * Sq + qr) * Dm + h * 64 + nd * 16 + l15;
        bf16 hi = (bf16)ov;
        chi[ad] = hi;
        clo[ad] = (bf16)(ov - (float)hi);
      }
}

// ---------------- launch ----------------
extern "C" void kernel_launch(void* const* d_in, const int* in_sizes, int n_in,
                              void* d_out, int out_size, void* d_ws, size_t ws_size,
                              hipStream_t stream) {
  const float* x  = (const float*)d_in[0];
  const float* Wq = (const float*)d_in[1];
  const float* Wk = (const float*)d_in[2];
  const float* Wv = (const float*)d_in[3];
  const float* Wo = (const float*)d_in[4];
  const float* bo = (const float*)d_in[5];
  const float* W1 = (const float*)d_in[6];
  const float* b1 = (const float*)d_in[7];
  const float* W2 = (const float*)d_in[8];
  const float* b2 = (const float*)d_in[9];
  const float* g1 = (const float*)d_in[10];
  const float* s1 = (const float*)d_in[11];
  const float* g2 = (const float*)d_in[12];
  const float* s2 = (const float*)d_in[13];
  float* out = (float*)d_out;

  if (ws_size < 150994944ULL) return; // need 144 MB

  char* ws = (char*)d_ws;
  // weights (48 MB)
  bf16* wqkvT_hi = (bf16*)(ws + 0);
  bf16* wqkvT_lo = (bf16*)(ws + 6291456);
  bf16* woT_hi   = (bf16*)(ws + 12582912);
  bf16* woT_lo   = (bf16*)(ws + 14680064);
  bf16* w1T_hi   = (bf16*)(ws + 16777216);
  bf16* w1T_lo   = (bf16*)(ws + 25165824);
  bf16* w2T_hi   = (bf16*)(ws + 33554432);
  bf16* w2T_lo   = (bf16*)(ws + 41943040);
  // region A (64 MB): h, q, k, vT  -> later a1
  char* rA = ws + 50331648;
  bf16* h_hi  = (bf16*)(rA + 0);
  bf16* h_lo  = (bf16*)(rA + 8388608);
  bf16* q_hi  = (bf16*)(rA + 16777216); // q_lo,k_hi,k_lo,vT_hi,vT_lo follow contiguously (EP_QKV offsets)
  bf16* q_lo  = (bf16*)(rA + 25165824);
  bf16* k_hi  = (bf16*)(rA + 33554432);
  bf16* k_lo  = (bf16*)(rA + 41943040);
  bf16* vT_hi = (bf16*)(rA + 50331648);
  bf16* vT_lo = (bf16*)(rA + 58720256);
  bf16* a1_hi = (bf16*)(rA + 0);        // 32 MB, reuses region A after attention
  bf16* a1_lo = (bf16*)(rA + 33554432);
  // region B (16 MB): ctx -> later h2
  char* rB = ws + 117440512;
  bf16* ctx_hi = (bf16*)(rB + 0);
  bf16* ctx_lo = (bf16*)(rB + 8388608);
  bf16* h2_hi  = (bf16*)(rB + 0);
  bf16* h2_lo  = (bf16*)(rB + 8388608);
  // region C (16 MB): x1 fp32
  float* x1 = (float*)(ws + 134217728);

  // 1) weight transforms
  transpose_split_kernel<<<dim3(16, 16), 256, 0, stream>>>(Wq, wqkvT_hi, wqkvT_lo, 1024, 1024);
  transpose_split_kernel<<<dim3(16, 16), 256, 0, stream>>>(Wk, wqkvT_hi + 1024 * 1024, wqkvT_lo + 1024 * 1024, 1024, 1024);
  transpose_split_kernel<<<dim3(16, 16), 256, 0, stream>>>(Wv, wqkvT_hi + 2048 * 1024, wqkvT_lo + 2048 * 1024, 1024, 1024);
  transpose_split_kernel<<<dim3(16, 16), 256, 0, stream>>>(Wo, woT_hi, woT_lo, 1024, 1024);
  transpose_split_kernel<<<dim3(64, 16), 256, 0, stream>>>(W1, w1T_hi, w1T_lo, 1024, 4096);
  transpose_split_kernel<<<dim3(16, 64), 256, 0, stream>>>(W2, w2T_hi, w2T_lo, 4096, 1024);

  // 2) LN1
  ln_split_kernel<<<4096, 256, 0, stream>>>(x, g1, s1, h_hi, h_lo);

  // 3) fused QKV GEMM (N = 3072)
  gemm_kernel<64, 0><<<dim3(24, 64), 256, 0, stream>>>(h_hi, h_lo, wqkvT_hi, wqkvT_lo,
                                                       1024, 3072, q_hi, nullptr, nullptr, nullptr, nullptr);
  // 4) attention
  attn_kernel<<<dim3(16, 32), 256, 0, stream>>>(q_hi, q_lo, k_hi, k_lo, vT_hi, vT_lo, ctx_hi, ctx_lo);

  // 5) Wo projection + bias + residual -> x1
  gemm_kernel<64, 1><<<dim3(8, 64), 256, 0, stream>>>(ctx_hi, ctx_lo, woT_hi, woT_lo,
                                                      1024, 1024, nullptr, nullptr, x1, bo, x);
  // 6) LN2
  ln_split_kernel<<<4096, 256, 0, stream>>>(x1, g2, s2, h2_hi, h2_lo);

  // 7) FFN up + GELU -> a1
  gemm_kernel<128, 2><<<dim3(32, 32), 256, 0, stream>>>(h2_hi, h2_lo, w1T_hi, w1T_lo,
                                                        1024, 4096, a1_hi, a1_lo, nullptr, b1, nullptr);
  // 8) FFN down + bias + residual -> out
  gemm_kernel<64, 1><<<dim3(8, 64), 256, 0, stream>>>(a1_hi, a1_lo, w2T_hi, w2T_lo,
                                                      4096, 1024, nullptr, nullptr, out, b2, x1);
}

// Round 2
// 669.124 us; speedup vs baseline: 1.2570x; 1.2570x over previous
//
#include <hip/hip_runtime.h>
#include <hip/hip_bf16.h>
#include <math.h>

typedef __bf16 bf16;
typedef __bf16 bf16x4 __attribute__((ext_vector_type(4)));
typedef __bf16 bf16x8 __attribute__((ext_vector_type(8)));
typedef float f32x4 __attribute__((ext_vector_type(4)));

#define DEV static __device__ __forceinline__

constexpr int Dm = 1024;   // model dim
constexpr int Sq = 2048;   // seq len
constexpr int Mrows = 4096; // B*S
constexpr size_t AE = (size_t)Mrows * Dm; // elems per activation array

DEV void gload_lds16(const void* g, void* l) {
  __builtin_amdgcn_global_load_lds((const __attribute__((address_space(1))) unsigned int*)g,
                                   (__attribute__((address_space(3))) unsigned int*)l,
                                   16, 0, 0);
}

DEV float gelu_f(float u) {
  const float c = 0.7978845608028654f; // sqrt(2/pi)
  float t = tanhf(c * (u + 0.044715f * u * u * u));
  return 0.5f * u * (1.0f + t);
}

// ---------------- weight transpose + hi/lo split: W[K][N] -> T[N][K] ----------------
__global__ void transpose_split_kernel(const float* __restrict__ W,
                                       bf16* __restrict__ Thi, bf16* __restrict__ Tlo,
                                       int K, int N) {
  __shared__ float tile[64][65];
  const int t = threadIdx.x;
  const int nt = blockIdx.x * 64, kt = blockIdx.y * 64;
  #pragma unroll
  for (int i = 0; i < 16; ++i) {
    int id = i * 256 + t;
    int r = id >> 6, c = id & 63;
    tile[r][c] = W[(size_t)(kt + r) * N + nt + c];
  }
  __syncthreads();
  #pragma unroll
  for (int i = 0; i < 16; ++i) {
    int id = i * 256 + t;
    int n = id >> 6, k = id & 63;
    float v = tile[k][n];
    bf16 hi = (bf16)v;
    size_t ad = (size_t)(nt + n) * K + kt + k;
    Thi[ad] = hi;
    Tlo[ad] = (bf16)(v - (float)hi);
  }
}

// ---------------- LayerNorm + hi/lo split (one block per row of 1024) ----------------
__global__ void ln_split_kernel(const float* __restrict__ x,
                                const float* __restrict__ gamma, const float* __restrict__ beta,
                                bf16* __restrict__ ohi, bf16* __restrict__ olo) {
  const int row = blockIdx.x, t = threadIdx.x;
  const float4 v = ((const float4*)(x + (size_t)row * Dm))[t];
  float s = v.x + v.y + v.z + v.w;
  float sq = v.x * v.x + v.y * v.y + v.z * v.z + v.w * v.w;
  #pragma unroll
  for (int off = 1; off < 64; off <<= 1) {
    s += __shfl_xor(s, off);
    sq += __shfl_xor(sq, off);
  }
  __shared__ float red[8];
  const int wave = t >> 6, lane = t & 63;
  if (lane == 0) { red[wave] = s; red[4 + wave] = sq; }
  __syncthreads();
  s = red[0] + red[1] + red[2] + red[3];
  sq = red[4] + red[5] + red[6] + red[7];
  const float mean = s * (1.0f / 1024.0f);
  const float var = sq * (1.0f / 1024.0f) - mean * mean;
  const float inv = 1.0f / sqrtf(var + 1e-5f);
  const float4 g4 = ((const float4*)gamma)[t];
  const float4 b4 = ((const float4*)beta)[t];
  float y[4];
  y[0] = (v.x - mean) * inv * g4.x + b4.x;
  y[1] = (v.y - mean) * inv * g4.y + b4.y;
  y[2] = (v.z - mean) * inv * g4.z + b4.z;
  y[3] = (v.w - mean) * inv * g4.w + b4.w;
  bf16x4 hv, lv;
  #pragma unroll
  for (int i = 0; i < 4; ++i) {
    bf16 hi = (bf16)y[i];
    hv[i] = hi;
    lv[i] = (bf16)(y[i] - (float)hi);
  }
  ((bf16x4*)(ohi + (size_t)row * Dm))[t] = hv;
  ((bf16x4*)(olo + (size_t)row * Dm))[t] = lv;
}

// ---------------- split-bf16 GEMM: C = (Ahi+Alo) @ (Bhi+Blo)^T(stored [N][K]) ----------------
// kt-outer: stage Ahi/Alo/Bhi/Blo once, 3 MFMA passes (hh, lh, hl). Tile 64x128, 4 waves (2x2).
// EP: 0 = QKV (write q/k natural + v transposed, hi/lo), 1 = bias+residual fp32, 2 = gelu+split.
template<int EP>
__global__ __launch_bounds__(256, 3) void gemm_kernel(
    const bf16* __restrict__ Ahi, const bf16* __restrict__ Alo,
    const bf16* __restrict__ Bthi, const bf16* __restrict__ Btlo,
    int K, int N,
    bf16* __restrict__ Ohi, bf16* __restrict__ Olo,
    float* __restrict__ Of,
    const float* __restrict__ bias, const float* __restrict__ resid) {
  const int t = threadIdx.x, wave = t >> 6, lane = t & 63;
  const int wr = wave >> 1, wc = wave & 1;
  const int l15 = lane & 15, l4 = lane >> 4;
  const int row0 = blockIdx.y * 64, col0 = blockIdx.x * 128;

  __shared__ __align__(16) bf16 sAh[64 * 64], sAl[64 * 64];
  __shared__ __align__(16) bf16 sBh[128 * 64], sBl[128 * 64];

  f32x4 acc[2][4];
  #pragma unroll
  for (int m = 0; m < 2; ++m)
    #pragma unroll
    for (int n = 0; n < 4; ++n)
      acc[m][n] = (f32x4){0.f, 0.f, 0.f, 0.f};

  for (int kt = 0; kt < K; kt += 64) {
    // stage A hi/lo [64][64] and B hi/lo [128][64]; global chunk pre-swizzled, LDS linear
    #pragma unroll
    for (int p = 0; p < 2; ++p) {
      int id = p * 256 + t;
      int r = id >> 3, c = id & 7;
      int cs = (c ^ (r & 7)) << 3;
      size_t ga = (size_t)(row0 + r) * K + kt + cs;
      gload_lds16(Ahi + ga, (char*)sAh + (p * 256 + wave * 64) * 16);
      gload_lds16(Alo + ga, (char*)sAl + (p * 256 + wave * 64) * 16);
    }
    #pragma unroll
    for (int p = 0; p < 4; ++p) {
      int id = p * 256 + t;
      int r = id >> 3, c = id & 7;
      int cs = (c ^ (r & 7)) << 3;
      size_t ga = (size_t)(col0 + r) * K + kt + cs;
      gload_lds16(Bthi + ga, (char*)sBh + (p * 256 + wave * 64) * 16);
      gload_lds16(Btlo + ga, (char*)sBl + (p * 256 + wave * 64) * 16);
    }
    __syncthreads();

    bf16x8 afh[2][2], afl[2][2], bfh[4][2], bfl[4][2];
    #pragma unroll
    for (int m = 0; m < 2; ++m)
      #pragma unroll
      for (int ks = 0; ks < 2; ++ks) {
        int r = wr * 32 + m * 16 + l15;
        int ch = ((ks * 4 + l4) ^ (r & 7)) << 3;
        afh[m][ks] = *(const bf16x8*)&sAh[r * 64 + ch];
        afl[m][ks] = *(const bf16x8*)&sAl[r * 64 + ch];
      }
    #pragma unroll
    for (int n = 0; n < 4; ++n)
      #pragma unroll
      for (int ks = 0; ks < 2; ++ks) {
        int r = wc * 64 + n * 16 + l15;
        int ch = ((ks * 4 + l4) ^ (r & 7)) << 3;
        bfh[n][ks] = *(const bf16x8*)&sBh[r * 64 + ch];
        bfl[n][ks] = *(const bf16x8*)&sBl[r * 64 + ch];
      }
    #pragma unroll
    for (int ks = 0; ks < 2; ++ks)
      #pragma unroll
      for (int m = 0; m < 2; ++m)
        #pragma unroll
        for (int n = 0; n < 4; ++n)
          acc[m][n] = __builtin_amdgcn_mfma_f32_16x16x32_bf16(afh[m][ks], bfh[n][ks], acc[m][n], 0, 0, 0);
    #pragma unroll
    for (int ks = 0; ks < 2; ++ks)
      #pragma unroll
      for (int m = 0; m < 2; ++m)
        #pragma unroll
        for (int n = 0; n < 4; ++n)
          acc[m][n] = __builtin_amdgcn_mfma_f32_16x16x32_bf16(afl[m][ks], bfh[n][ks], acc[m][n], 0, 0, 0);
    #pragma unroll
    for (int ks = 0; ks < 2; ++ks)
      #pragma unroll
      for (int m = 0; m < 2; ++m)
        #pragma unroll
        for (int n = 0; n < 4; ++n)
          acc[m][n] = __builtin_amdgcn_mfma_f32_16x16x32_bf16(afh[m][ks], bfl[n][ks], acc[m][n], 0, 0, 0);
    __syncthreads();
  }

  // epilogue
  #pragma unroll
  for (int m = 0; m < 2; ++m)
    #pragma unroll
    for (int n = 0; n < 4; ++n)
      #pragma unroll
      for (int rr = 0; rr < 4; ++rr) {
        int row = row0 + wr * 32 + m * 16 + l4 * 4 + rr;
        int col = col0 + wc * 64 + n * 16 + l15;
        float v = acc[m][n][rr];
        if constexpr (EP == 0) {
          int which = col >> 10;
          int c = col & 1023;
          bf16 hi = (bf16)v;
          bf16 lo = (bf16)(v - (float)hi);
          if (which == 0) {
            size_t ad = (size_t)row * Dm + c;
            Ohi[ad] = hi; Ohi[AE + ad] = lo;               // q hi/lo
          } else if (which == 1) {
            size_t ad = (size_t)row * Dm + c;
            Ohi[2 * AE + ad] = hi; Ohi[3 * AE + ad] = lo;  // k hi/lo
          } else {
            size_t ad = ((size_t)(row >> 11) * Dm + c) * Sq + (row & (Sq - 1));
            Ohi[4 * AE + ad] = hi; Ohi[5 * AE + ad] = lo;  // v transposed [b][h*64+hd][s]
          }
        } else if constexpr (EP == 1) {
          size_t ad = (size_t)row * N + col;
          Of[ad] = v + bias[col] + resid[ad];
        } else {
          float u = gelu_f(v + bias[col]);
          bf16 hi = (bf16)u;
          size_t ad = (size_t)row * N + col;
          Ohi[ad] = hi;
          Olo[ad] = (bf16)(u - (float)hi);
        }
      }
}

// ---------------- causal flash attention, split-bf16 MFMA ----------------
// grid: (S/64, B*H). 4 waves; wave w owns ONE 16-row q fragment -> every wave active every kb.
__global__ __launch_bounds__(256, 3) void attn_kernel(
    const bf16* __restrict__ qhi, const bf16* __restrict__ qlo,
    const bf16* __restrict__ khi, const bf16* __restrict__ klo,
    const bf16* __restrict__ vthi, const bf16* __restrict__ vtlo,
    bf16* __restrict__ chi, bf16* __restrict__ clo) {
  const int t = threadIdx.x, wave = t >> 6, lane = t & 63;
  const int l15 = lane & 15, l4 = lane >> 4;
  const int qt = blockIdx.x, bh = blockIdx.y;
  const int b = bh >> 4, h = bh & 15;
  const int qb = qt * 64;
  const int q0 = qb + wave * 16;
  const float SC = 0.125f * 1.4426950408889634f; // (1/sqrt(64)) * log2(e)

  __shared__ __align__(16) bf16 sKh[64 * 64], sKl[64 * 64], sVh[64 * 64], sVl[64 * 64];
  __shared__ __align__(16) bf16 sPh[64 * 64], sPl[64 * 64];

  // hoist Q fragments (hi and lo)
  bf16x8 qfh[2], qfl[2];
  #pragma unroll
  for (int ks = 0; ks < 2; ++ks) {
    size_t ad = (size_t)(b * Sq + q0 + l15) * Dm + h * 64 + ks * 32 + l4 * 8;
    qfh[ks] = *(const bf16x8*)&qhi[ad];
    qfl[ks] = *(const bf16x8*)&qlo[ad];
  }

  f32x4 cacc[4];
  float mrun[4], lrun[4];
  #pragma unroll
  for (int nd = 0; nd < 4; ++nd) cacc[nd] = (f32x4){0.f, 0.f, 0.f, 0.f};
  #pragma unroll
  for (int rr = 0; rr < 4; ++rr) { mrun[rr] = -3e38f; lrun[rr] = 0.f; }

  for (int kb = 0; kb <= qb; kb += 64) {
    // stage K hi/lo [64 s][64 d] and V^T hi/lo [64 d][64 s]
    #pragma unroll
    for (int p = 0; p < 2; ++p) {
      int id = p * 256 + t;
      int r = id >> 3, c = id & 7;
      int cc = (c ^ (r & 7)) << 3;
      size_t ka = (size_t)(b * Sq + kb + r) * Dm + h * 64 + cc;
      size_t va = (size_t)(b * Dm + h * 64 + r) * Sq + kb + cc;
      gload_lds16(&khi[ka], (char*)sKh + (p * 256 + wave * 64) * 16);
      gload_lds16(&klo[ka], (char*)sKl + (p * 256 + wave * 64) * 16);
      gload_lds16(&vthi[va], (char*)sVh + (p * 256 + wave * 64) * 16);
      gload_lds16(&vtlo[va], (char*)sVl + (p * 256 + wave * 64) * 16);
    }
    __syncthreads();

    // ---------- S = Q K^T (3 split passes) ----------
    f32x4 sacc[4];
    #pragma unroll
    for (int nk = 0; nk < 4; ++nk) sacc[nk] = (f32x4){0.f, 0.f, 0.f, 0.f};
    {
      bf16x8 kfh[4][2], kfl[4][2];
      #pragma unroll
      for (int nk = 0; nk < 4; ++nk)
        #pragma unroll
        for (int ks = 0; ks < 2; ++ks) {
          int r = nk * 16 + l15;
          int ch = ((ks * 4 + l4) ^ (r & 7)) << 3;
          kfh[nk][ks] = *(const bf16x8*)&sKh[r * 64 + ch];
          kfl[nk][ks] = *(const bf16x8*)&sKl[r * 64 + ch];
        }
      #pragma unroll
      for (int ks = 0; ks < 2; ++ks)
        #pragma unroll
        for (int nk = 0; nk < 4; ++nk)
          sacc[nk] = __builtin_amdgcn_mfma_f32_16x16x32_bf16(qfh[ks], kfh[nk][ks], sacc[nk], 0, 0, 0);
      #pragma unroll
      for (int ks = 0; ks < 2; ++ks)
        #pragma unroll
        for (int nk = 0; nk < 4; ++nk)
          sacc[nk] = __builtin_amdgcn_mfma_f32_16x16x32_bf16(qfl[ks], kfh[nk][ks], sacc[nk], 0, 0, 0);
      #pragma unroll
      for (int ks = 0; ks < 2; ++ks)
        #pragma unroll
        for (int nk = 0; nk < 4; ++nk)
          sacc[nk] = __builtin_amdgcn_mfma_f32_16x16x32_bf16(qfh[ks], kfl[nk][ks], sacc[nk], 0, 0, 0);
    }

    // ---------- scale (log2 domain), causal mask (diagonal block only), online softmax ----------
    const bool diag = (kb == qb);
    #pragma unroll
    for (int rr = 0; rr < 4; ++rr) {
      float mx = -3e38f;
      #pragma unroll
      for (int nk = 0; nk < 4; ++nk) {
        float tv = sacc[nk][rr] * SC;
        if (diag && (nk * 16 + l15 > wave * 16 + l4 * 4 + rr)) tv = -3e38f;
        sacc[nk][rr] = tv;
        mx = fmaxf(mx, tv);
      }
      mx = fmaxf(mx, __shfl_xor(mx, 1));
      mx = fmaxf(mx, __shfl_xor(mx, 2));
      mx = fmaxf(mx, __shfl_xor(mx, 4));
      mx = fmaxf(mx, __shfl_xor(mx, 8));
      float mold = mrun[rr];
      if (mx > mold + 8.0f) {        // defer-max: only rescale on big jumps
        float corr = exp2f(mold - mx);
        lrun[rr] *= corr;
        #pragma unroll
        for (int nd = 0; nd < 4; ++nd) cacc[nd][rr] *= corr;
        mrun[rr] = mx;
        mold = mx;
      }
      float rs = 0.f;
      #pragma unroll
      for (int nk = 0; nk < 4; ++nk) {
        float p = exp2f(sacc[nk][rr] - mold);
        sacc[nk][rr] = p;
        rs += p;
      }
      rs += __shfl_xor(rs, 1);
      rs += __shfl_xor(rs, 2);
      rs += __shfl_xor(rs, 4);
      rs += __shfl_xor(rs, 8);
      lrun[rr] += rs;
    }

    // ---------- write P (hi/lo) to swizzled LDS (wave-private rows) ----------
    #pragma unroll
    for (int nk = 0; nk < 4; ++nk)
      #pragma unroll
      for (int rr = 0; rr < 4; ++rr) {
        int row = wave * 16 + l4 * 4 + rr;
        int col = nk * 16 + l15;
        int ad = row * 64 + (((col >> 3) ^ (row & 7)) << 3) + (col & 7);
        float p = sacc[nk][rr];
        bf16 ph = (bf16)p;
        sPh[ad] = ph;
        sPl[ad] = (bf16)(p - (float)ph);
      }

    // ---------- ctx += P V (3 split passes) ----------
    {
      bf16x8 pfh[2], pfl[2];
      #pragma unroll
      for (int ks = 0; ks < 2; ++ks) {
        int r = wave * 16 + l15;
        int ch = ((ks * 4 + l4) ^ (r & 7)) << 3;
        pfh[ks] = *(const bf16x8*)&sPh[r * 64 + ch];
        pfl[ks] = *(const bf16x8*)&sPl[r * 64 + ch];
      }
      bf16x8 vfh[2][4], vfl[2][4];
      #pragma unroll
      for (int ks = 0; ks < 2; ++ks)
        #pragma unroll
        for (int nd = 0; nd < 4; ++nd) {
          int r = nd * 16 + l15;
          int ch = ((ks * 4 + l4) ^ (r & 7)) << 3;
          vfh[ks][nd] = *(const bf16x8*)&sVh[r * 64 + ch];
          vfl[ks][nd] = *(const bf16x8*)&sVl[r * 64 + ch];
        }
      #pragma unroll
      for (int ks = 0; ks < 2; ++ks)
        #pragma unroll
        for (int nd = 0; nd < 4; ++nd)
          cacc[nd] = __builtin_amdgcn_mfma_f32_16x16x32_bf16(pfh[ks], vfh[ks][nd], cacc[nd], 0, 0, 0);
      #pragma unroll
      for (int ks = 0; ks < 2; ++ks)
        #pragma unroll
        for (int nd = 0; nd < 4; ++nd)
          cacc[nd] = __builtin_amdgcn_mfma_f32_16x16x32_bf16(pfl[ks], vfh[ks][nd], cacc[nd], 0, 0, 0);
      #pragma unroll
      for (int ks = 0; ks < 2; ++ks)
        #pragma unroll
        for (int nd = 0; nd < 4; ++nd)
          cacc[nd] = __builtin_amdgcn_mfma_f32_16x16x32_bf16(pfh[ks], vfl[ks][nd], cacc[nd], 0, 0, 0);
    }
    __syncthreads();
  }

  // epilogue: ctx / l, split, store natural layout
  #pragma unroll
  for (int rr = 0; rr < 4; ++rr) {
    float rcp = 1.0f / lrun[rr];
    int qr = q0 + l4 * 4 + rr;
    #pragma unroll
    for (int nd = 0; nd < 4; ++nd) {
      float ov = cacc[nd][rr] * rcp;
      size_t ad = (size_t)(b * Sq + qr) * Dm + h * 64 + nd * 16 + l15;
      bf16 hi = (bf16)ov;
      chi[ad] = hi;
      clo[ad] = (bf16)(ov - (float)hi);
    }
  }
}

// ---------------- launch ----------------
extern "C" void kernel_launch(void* const* d_in, const int* in_sizes, int n_in,
                              void* d_out, int out_size, void* d_ws, size_t ws_size,
                              hipStream_t stream) {
  const float* x  = (const float*)d_in[0];
  const float* Wq = (const float*)d_in[1];
  const float* Wk = (const float*)d_in[2];
  const float* Wv = (const float*)d_in[3];
  const float* Wo = (const float*)d_in[4];
  const float* bo = (const float*)d_in[5];
  const float* W1 = (const float*)d_in[6];
  const float* b1 = (const float*)d_in[7];
  const float* W2 = (const float*)d_in[8];
  const float* b2 = (const float*)d_in[9];
  const float* g1 = (const float*)d_in[10];
  const float* s1 = (const float*)d_in[11];
  const float* g2 = (const float*)d_in[12];
  const float* s2 = (const float*)d_in[13];
  float* out = (float*)d_out;

  if (ws_size < 150994944ULL) return; // need 144 MB

  char* ws = (char*)d_ws;
  // weights (48 MB)
  bf16* wqkvT_hi = (bf16*)(ws + 0);
  bf16* wqkvT_lo = (bf16*)(ws + 6291456);
  bf16* woT_hi   = (bf16*)(ws + 12582912);
  bf16* woT_lo   = (bf16*)(ws + 14680064);
  bf16* w1T_hi   = (bf16*)(ws + 16777216);
  bf16* w1T_lo   = (bf16*)(ws + 25165824);
  bf16* w2T_hi   = (bf16*)(ws + 33554432);
  bf16* w2T_lo   = (bf16*)(ws + 41943040);
  // region A (64 MB): h, q, k, vT  -> later a1
  char* rA = ws + 50331648;
  bf16* h_hi  = (bf16*)(rA + 0);
  bf16* h_lo  = (bf16*)(rA + 8388608);
  bf16* q_hi  = (bf16*)(rA + 16777216); // q_lo,k_hi,k_lo,vT_hi,vT_lo follow contiguously (EP0 offsets)
  bf16* q_lo  = (bf16*)(rA + 25165824);
  bf16* k_hi  = (bf16*)(rA + 33554432);
  bf16* k_lo  = (bf16*)(rA + 41943040);
  bf16* vT_hi = (bf16*)(rA + 50331648);
  bf16* vT_lo = (bf16*)(rA + 58720256);
  bf16* a1_hi = (bf16*)(rA + 0);        // 32 MB, reuses region A after attention
  bf16* a1_lo = (bf16*)(rA + 33554432);
  // region B (16 MB): ctx -> later h2
  char* rB = ws + 117440512;
  bf16* ctx_hi = (bf16*)(rB + 0);
  bf16* ctx_lo = (bf16*)(rB + 8388608);
  bf16* h2_hi  = (bf16*)(rB + 0);
  bf16* h2_lo  = (bf16*)(rB + 8388608);
  // region C (16 MB): x1 fp32
  float* x1 = (float*)(ws + 134217728);

  // 1) weight transforms
  transpose_split_kernel<<<dim3(16, 16), 256, 0, stream>>>(Wq, wqkvT_hi, wqkvT_lo, 1024, 1024);
  transpose_split_kernel<<<dim3(16, 16), 256, 0, stream>>>(Wk, wqkvT_hi + 1024 * 1024, wqkvT_lo + 1024 * 1024, 1024, 1024);
  transpose_split_kernel<<<dim3(16, 16), 256, 0, stream>>>(Wv, wqkvT_hi + 2048 * 1024, wqkvT_lo + 2048 * 1024, 1024, 1024);
  transpose_split_kernel<<<dim3(16, 16), 256, 0, stream>>>(Wo, woT_hi, woT_lo, 1024, 1024);
  transpose_split_kernel<<<dim3(64, 16), 256, 0, stream>>>(W1, w1T_hi, w1T_lo, 1024, 4096);
  transpose_split_kernel<<<dim3(16, 64), 256, 0, stream>>>(W2, w2T_hi, w2T_lo, 4096, 1024);

  // 2) LN1
  ln_split_kernel<<<4096, 256, 0, stream>>>(x, g1, s1, h_hi, h_lo);

  // 3) fused QKV GEMM (N = 3072)
  gemm_kernel<0><<<dim3(24, 64), 256, 0, stream>>>(h_hi, h_lo, wqkvT_hi, wqkvT_lo,
                                                   1024, 3072, q_hi, nullptr, nullptr, nullptr, nullptr);
  // 4) attention
  attn_kernel<<<dim3(32, 32), 256, 0, stream>>>(q_hi, q_lo, k_hi, k_lo, vT_hi, vT_lo, ctx_hi, ctx_lo);

  // 5) Wo projection + bias + residual -> x1
  gemm_kernel<1><<<dim3(8, 64), 256, 0, stream>>>(ctx_hi, ctx_lo, woT_hi, woT_lo,
                                                  1024, 1024, nullptr, nullptr, x1, bo, x);
  // 6) LN2
  ln_split_kernel<<<4096, 256, 0, stream>>>(x1, g2, s2, h2_hi, h2_lo);

  // 7) FFN up + GELU -> a1
  gemm_kernel<2><<<dim3(32, 64), 256, 0, stream>>>(h2_hi, h2_lo, w1T_hi, w1T_lo,
                                                   1024, 4096, a1_hi, a1_lo, nullptr, b1, nullptr);
  // 8) FFN down + bias + residual -> out
  gemm_kernel<1><<<dim3(8, 64), 256, 0, stream>>>(a1_hi, a1_lo, w2T_hi, w2T_lo,
                                                  4096, 1024, nullptr, nullptr, out, b2, x1);
}

// Round 3
// 562.584 us; speedup vs baseline: 1.4951x; 1.1894x over previous
//
#include <hip/hip_runtime.h>
#include <hip/hip_bf16.h>
#include <math.h>

typedef __bf16 bf16;
typedef __bf16 bf16x4 __attribute__((ext_vector_type(4)));
typedef __bf16 bf16x8 __attribute__((ext_vector_type(8)));
typedef float f32x4 __attribute__((ext_vector_type(4)));

#define DEV static __device__ __forceinline__

constexpr int Dm = 1024;   // model dim
constexpr int Sq = 2048;   // seq len
constexpr int Mrows = 4096; // B*S
constexpr size_t AE = (size_t)Mrows * Dm; // elems per activation array

DEV void gload_lds16(const void* g, void* l) {
  __builtin_amdgcn_global_load_lds((const __attribute__((address_space(1))) unsigned int*)g,
                                   (__attribute__((address_space(3))) unsigned int*)l,
                                   16, 0, 0);
}

DEV float gelu_f(float u) {
  const float c = 0.7978845608028654f; // sqrt(2/pi)
  float t = tanhf(c * (u + 0.044715f * u * u * u));
  return 0.5f * u * (1.0f + t);
}

// ---------------- weight transpose + hi/lo split: W[K][N] -> T[N][K] ----------------
__global__ void transpose_split_kernel(const float* __restrict__ W,
                                       bf16* __restrict__ Thi, bf16* __restrict__ Tlo,
                                       int K, int N) {
  __shared__ float tile[64][65];
  const int t = threadIdx.x;
  const int nt = blockIdx.x * 64, kt = blockIdx.y * 64;
  #pragma unroll
  for (int i = 0; i < 16; ++i) {
    int id = i * 256 + t;
    int r = id >> 6, c = id & 63;
    tile[r][c] = W[(size_t)(kt + r) * N + nt + c];
  }
  __syncthreads();
  #pragma unroll
  for (int i = 0; i < 16; ++i) {
    int id = i * 256 + t;
    int n = id >> 6, k = id & 63;
    float v = tile[k][n];
    bf16 hi = (bf16)v;
    size_t ad = (size_t)(nt + n) * K + kt + k;
    Thi[ad] = hi;
    Tlo[ad] = (bf16)(v - (float)hi);
  }
}

// ---------------- LayerNorm + hi/lo split (one block per row of 1024) ----------------
__global__ void ln_split_kernel(const float* __restrict__ x,
                                const float* __restrict__ gamma, const float* __restrict__ beta,
                                bf16* __restrict__ ohi, bf16* __restrict__ olo) {
  const int row = blockIdx.x, t = threadIdx.x;
  const float4 v = ((const float4*)(x + (size_t)row * Dm))[t];
  float s = v.x + v.y + v.z + v.w;
  float sq = v.x * v.x + v.y * v.y + v.z * v.z + v.w * v.w;
  #pragma unroll
  for (int off = 1; off < 64; off <<= 1) {
    s += __shfl_xor(s, off);
    sq += __shfl_xor(sq, off);
  }
  __shared__ float red[8];
  const int wave = t >> 6, lane = t & 63;
  if (lane == 0) { red[wave] = s; red[4 + wave] = sq; }
  __syncthreads();
  s = red[0] + red[1] + red[2] + red[3];
  sq = red[4] + red[5] + red[6] + red[7];
  const float mean = s * (1.0f / 1024.0f);
  const float var = sq * (1.0f / 1024.0f) - mean * mean;
  const float inv = 1.0f / sqrtf(var + 1e-5f);
  const float4 g4 = ((const float4*)gamma)[t];
  const float4 b4 = ((const float4*)beta)[t];
  float y[4];
  y[0] = (v.x - mean) * inv * g4.x + b4.x;
  y[1] = (v.y - mean) * inv * g4.y + b4.y;
  y[2] = (v.z - mean) * inv * g4.z + b4.z;
  y[3] = (v.w - mean) * inv * g4.w + b4.w;
  bf16x4 hv, lv;
  #pragma unroll
  for (int i = 0; i < 4; ++i) {
    bf16 hi = (bf16)y[i];
    hv[i] = hi;
    lv[i] = (bf16)(y[i] - (float)hi);
  }
  ((bf16x4*)(ohi + (size_t)row * Dm))[t] = hv;
  ((bf16x4*)(olo + (size_t)row * Dm))[t] = lv;
}

// ---------------- split-bf16 GEMM: C = (Ahi+Alo) @ (Bhi+Blo)^T(stored [N][K]) ----------------
// kt-outer: stage Ahi/Alo/Bhi/Blo once, 3 MFMA passes (hh, lh, hl). Tile 64x128, 4 waves (2x2).
// EP: 0 = QKV (q pre-scaled hi/lo, k hi, v transposed hi), 1 = bias+residual fp32, 2 = gelu+split.
template<int EP>
__global__ __launch_bounds__(256, 3) void gemm_kernel(
    const bf16* __restrict__ Ahi, const bf16* __restrict__ Alo,
    const bf16* __restrict__ Bthi, const bf16* __restrict__ Btlo,
    int K, int N,
    bf16* __restrict__ Ohi, bf16* __restrict__ Olo,
    float* __restrict__ Of,
    const float* __restrict__ bias, const float* __restrict__ resid) {
  const int t = threadIdx.x, wave = t >> 6, lane = t & 63;
  const int wr = wave >> 1, wc = wave & 1;
  const int l15 = lane & 15, l4 = lane >> 4;
  const int row0 = blockIdx.y * 64, col0 = blockIdx.x * 128;

  __shared__ __align__(16) bf16 sAh[64 * 64], sAl[64 * 64];
  __shared__ __align__(16) bf16 sBh[128 * 64], sBl[128 * 64];

  f32x4 acc[2][4];
  #pragma unroll
  for (int m = 0; m < 2; ++m)
    #pragma unroll
    for (int n = 0; n < 4; ++n)
      acc[m][n] = (f32x4){0.f, 0.f, 0.f, 0.f};

  for (int kt = 0; kt < K; kt += 64) {
    // stage A hi/lo [64][64] and B hi/lo [128][64]; global chunk pre-swizzled, LDS linear
    #pragma unroll
    for (int p = 0; p < 2; ++p) {
      int id = p * 256 + t;
      int r = id >> 3, c = id & 7;
      int cs = (c ^ (r & 7)) << 3;
      size_t ga = (size_t)(row0 + r) * K + kt + cs;
      gload_lds16(Ahi + ga, (char*)sAh + (p * 256 + wave * 64) * 16);
      gload_lds16(Alo + ga, (char*)sAl + (p * 256 + wave * 64) * 16);
    }
    #pragma unroll
    for (int p = 0; p < 4; ++p) {
      int id = p * 256 + t;
      int r = id >> 3, c = id & 7;
      int cs = (c ^ (r & 7)) << 3;
      size_t ga = (size_t)(col0 + r) * K + kt + cs;
      gload_lds16(Bthi + ga, (char*)sBh + (p * 256 + wave * 64) * 16);
      gload_lds16(Btlo + ga, (char*)sBl + (p * 256 + wave * 64) * 16);
    }
    __syncthreads();

    bf16x8 afh[2][2], afl[2][2], bfh[4][2], bfl[4][2];
    #pragma unroll
    for (int m = 0; m < 2; ++m)
      #pragma unroll
      for (int ks = 0; ks < 2; ++ks) {
        int r = wr * 32 + m * 16 + l15;
        int ch = ((ks * 4 + l4) ^ (r & 7)) << 3;
        afh[m][ks] = *(const bf16x8*)&sAh[r * 64 + ch];
        afl[m][ks] = *(const bf16x8*)&sAl[r * 64 + ch];
      }
    #pragma unroll
    for (int n = 0; n < 4; ++n)
      #pragma unroll
      for (int ks = 0; ks < 2; ++ks) {
        int r = wc * 64 + n * 16 + l15;
        int ch = ((ks * 4 + l4) ^ (r & 7)) << 3;
        bfh[n][ks] = *(const bf16x8*)&sBh[r * 64 + ch];
        bfl[n][ks] = *(const bf16x8*)&sBl[r * 64 + ch];
      }
    #pragma unroll
    for (int ks = 0; ks < 2; ++ks)
      #pragma unroll
      for (int m = 0; m < 2; ++m)
        #pragma unroll
        for (int n = 0; n < 4; ++n)
          acc[m][n] = __builtin_amdgcn_mfma_f32_16x16x32_bf16(afh[m][ks], bfh[n][ks], acc[m][n], 0, 0, 0);
    #pragma unroll
    for (int ks = 0; ks < 2; ++ks)
      #pragma unroll
      for (int m = 0; m < 2; ++m)
        #pragma unroll
        for (int n = 0; n < 4; ++n)
          acc[m][n] = __builtin_amdgcn_mfma_f32_16x16x32_bf16(afl[m][ks], bfh[n][ks], acc[m][n], 0, 0, 0);
    #pragma unroll
    for (int ks = 0; ks < 2; ++ks)
      #pragma unroll
      for (int m = 0; m < 2; ++m)
        #pragma unroll
        for (int n = 0; n < 4; ++n)
          acc[m][n] = __builtin_amdgcn_mfma_f32_16x16x32_bf16(afh[m][ks], bfl[n][ks], acc[m][n], 0, 0, 0);
    __syncthreads();
  }

  // epilogue
  #pragma unroll
  for (int m = 0; m < 2; ++m)
    #pragma unroll
    for (int n = 0; n < 4; ++n)
      #pragma unroll
      for (int rr = 0; rr < 4; ++rr) {
        int row = row0 + wr * 32 + m * 16 + l4 * 4 + rr;
        int col = col0 + wc * 64 + n * 16 + l15;
        float v = acc[m][n][rr];
        if constexpr (EP == 0) {
          int which = col >> 10;
          int c = col & 1023;
          if (which == 0) {
            float q = v * 0.18033688011111793f;  // 0.125 * log2(e) pre-folded into Q
            bf16 hi = (bf16)q;
            size_t ad = (size_t)row * Dm + c;
            Ohi[ad] = hi; Ohi[AE + ad] = (bf16)(q - (float)hi);  // q hi/lo
          } else if (which == 1) {
            size_t ad = (size_t)row * Dm + c;
            Ohi[2 * AE + ad] = (bf16)v;                          // k hi only
          } else {
            size_t ad = ((size_t)(row >> 11) * Dm + c) * Sq + (row & (Sq - 1));
            Ohi[4 * AE + ad] = (bf16)v;                          // v transposed hi only
          }
        } else if constexpr (EP == 1) {
          size_t ad = (size_t)row * N + col;
          Of[ad] = v + bias[col] + resid[ad];
        } else {
          float u = gelu_f(v + bias[col]);
          bf16 hi = (bf16)u;
          size_t ad = (size_t)row * N + col;
          Ohi[ad] = hi;
          Olo[ad] = (bf16)(u - (float)hi);
        }
      }
}

// ---------------- causal flash attention, double-buffered K/V, Q-split x bf16 K/V ----------------
// grid: (16, B*H). Each block does q-tiles {31-bx, bx} -> uniform 33 KV-iterations per block.
// 4 waves; wave w owns one 16-row q fragment. 2-phase pipeline: stage(next) issued before compute(cur).
__global__ __launch_bounds__(256, 2) void attn_kernel(
    const bf16* __restrict__ qhi, const bf16* __restrict__ qlo,
    const bf16* __restrict__ khi, const bf16* __restrict__ vthi,
    bf16* __restrict__ chi, bf16* __restrict__ clo) {
  const int t = threadIdx.x, wave = t >> 6, lane = t & 63;
  const int l15 = lane & 15, l4 = lane >> 4;
  const int bh = blockIdx.y;
  const int b = bh >> 4, h = bh & 15;

  __shared__ __align__(16) bf16 sK[2][4096], sV[2][4096], sP[4096];

  for (int half = 0; half < 2; ++half) {
    const int qt = (half == 0) ? (31 - (int)blockIdx.x) : (int)blockIdx.x;
    const int qb = qt * 64;
    const int q0 = qb + wave * 16;

    // hoist Q fragments (hi and lo); Q is pre-scaled by 0.125*log2e
    bf16x8 qfh[2], qfl[2];
    #pragma unroll
    for (int ks = 0; ks < 2; ++ks) {
      size_t ad = (size_t)(b * Sq + q0 + l15) * Dm + h * 64 + ks * 32 + l4 * 8;
      qfh[ks] = *(const bf16x8*)&qhi[ad];
      qfl[ks] = *(const bf16x8*)&qlo[ad];
    }

    f32x4 cacc[4];
    float mrun[4], lrun[4];
    #pragma unroll
    for (int nd = 0; nd < 4; ++nd) cacc[nd] = (f32x4){0.f, 0.f, 0.f, 0.f};
    #pragma unroll
    for (int rr = 0; rr < 4; ++rr) { mrun[rr] = -3e38f; lrun[rr] = 0.f; }

    auto STAGE = [&](int bb, int kb) {
      #pragma unroll
      for (int p = 0; p < 2; ++p) {
        int id = p * 256 + t;
        int r = id >> 3, c = id & 7;
        int cc = (c ^ (r & 7)) << 3;
        size_t ka = (size_t)(b * Sq + kb + r) * Dm + h * 64 + cc;
        size_t va = (size_t)(b * Dm + h * 64 + r) * Sq + kb + cc;
        gload_lds16(&khi[ka], (char*)&sK[bb][0] + (p * 256 + wave * 64) * 16);
        gload_lds16(&vthi[va], (char*)&sV[bb][0] + (p * 256 + wave * 64) * 16);
      }
    };

    // prologue: stage first tile
    STAGE(0, 0);
    __syncthreads();
    int cur = 0;

    for (int kb = 0; kb <= qb; kb += 64) {
      // issue next tile's staging early (hides HBM/L2 latency under compute)
      if (kb + 64 <= qb) STAGE(cur ^ 1, kb + 64);

      // ---------- S = Q K^T (q_hi + q_lo passes) ----------
      f32x4 sacc[4];
      #pragma unroll
      for (int nk = 0; nk < 4; ++nk) sacc[nk] = (f32x4){0.f, 0.f, 0.f, 0.f};
      {
        bf16x8 kf[4][2];
        #pragma unroll
        for (int nk = 0; nk < 4; ++nk)
          #pragma unroll
          for (int ks = 0; ks < 2; ++ks) {
            int r = nk * 16 + l15;
            int ch = ((ks * 4 + l4) ^ (r & 7)) << 3;
            kf[nk][ks] = *(const bf16x8*)&sK[cur][r * 64 + ch];
          }
        #pragma unroll
        for (int ks = 0; ks < 2; ++ks)
          #pragma unroll
          for (int nk = 0; nk < 4; ++nk)
            sacc[nk] = __builtin_amdgcn_mfma_f32_16x16x32_bf16(qfh[ks], kf[nk][ks], sacc[nk], 0, 0, 0);
        #pragma unroll
        for (int ks = 0; ks < 2; ++ks)
          #pragma unroll
          for (int nk = 0; nk < 4; ++nk)
            sacc[nk] = __builtin_amdgcn_mfma_f32_16x16x32_bf16(qfl[ks], kf[nk][ks], sacc[nk], 0, 0, 0);
      }

      // ---------- causal mask (diagonal block only), online softmax in log2 domain ----------
      const bool diag = (kb == qb);
      #pragma unroll
      for (int rr = 0; rr < 4; ++rr) {
        float mx = -3e38f;
        #pragma unroll
        for (int nk = 0; nk < 4; ++nk) {
          float tv = sacc[nk][rr];
          if (diag && (nk * 16 + l15 > wave * 16 + l4 * 4 + rr)) tv = -3e38f;
          sacc[nk][rr] = tv;
          mx = fmaxf(mx, tv);
        }
        mx = fmaxf(mx, __shfl_xor(mx, 1));
        mx = fmaxf(mx, __shfl_xor(mx, 2));
        mx = fmaxf(mx, __shfl_xor(mx, 4));
        mx = fmaxf(mx, __shfl_xor(mx, 8));
        float mold = mrun[rr];
        if (mx > mold + 8.0f) {        // defer-max: only rescale on big jumps
          float corr = exp2f(mold - mx);
          lrun[rr] *= corr;
          #pragma unroll
          for (int nd = 0; nd < 4; ++nd) cacc[nd][rr] *= corr;
          mrun[rr] = mx;
          mold = mx;
        }
        float rs = 0.f;
        #pragma unroll
        for (int nk = 0; nk < 4; ++nk) {
          float p = exp2f(sacc[nk][rr] - mold);
          sacc[nk][rr] = p;
          rs += p;
        }
        rs += __shfl_xor(rs, 1);
        rs += __shfl_xor(rs, 2);
        rs += __shfl_xor(rs, 4);
        rs += __shfl_xor(rs, 8);
        lrun[rr] += rs;
      }

      // ---------- write P (bf16) to swizzled LDS (wave-private rows) ----------
      #pragma unroll
      for (int nk = 0; nk < 4; ++nk)
        #pragma unroll
        for (int rr = 0; rr < 4; ++rr) {
          int row = wave * 16 + l4 * 4 + rr;
          int col = nk * 16 + l15;
          int ad = row * 64 + (((col >> 3) ^ (row & 7)) << 3) + (col & 7);
          sP[ad] = (bf16)sacc[nk][rr];
        }

      // ---------- ctx += P V ----------
      {
        bf16x8 pf[2];
        #pragma unroll
        for (int ks = 0; ks < 2; ++ks) {
          int r = wave * 16 + l15;
          int ch = ((ks * 4 + l4) ^ (r & 7)) << 3;
          pf[ks] = *(const bf16x8*)&sP[r * 64 + ch];
        }
        bf16x8 vf[2][4];
        #pragma unroll
        for (int ks = 0; ks < 2; ++ks)
          #pragma unroll
          for (int nd = 0; nd < 4; ++nd) {
            int r = nd * 16 + l15;
            int ch = ((ks * 4 + l4) ^ (r & 7)) << 3;
            vf[ks][nd] = *(const bf16x8*)&sV[cur][r * 64 + ch];
          }
        #pragma unroll
        for (int ks = 0; ks < 2; ++ks)
          #pragma unroll
          for (int nd = 0; nd < 4; ++nd)
            cacc[nd] = __builtin_amdgcn_mfma_f32_16x16x32_bf16(pf[ks], vf[ks][nd], cacc[nd], 0, 0, 0);
      }
      __syncthreads();  // drains next-tile staging (vmcnt) + guards buf reuse
      cur ^= 1;
    }

    // epilogue: ctx / l, split, store natural layout
    #pragma unroll
    for (int rr = 0; rr < 4; ++rr) {
      float rcp = 1.0f / lrun[rr];
      int qr = q0 + l4 * 4 + rr;
      #pragma unroll
      for (int nd = 0; nd < 4; ++nd) {
        float ov = cacc[nd][rr] * rcp;
        size_t ad = (size_t)(b * Sq + qr) * Dm + h * 64 + nd * 16 + l15;
        bf16 hi = (bf16)ov;
        chi[ad] = hi;
        clo[ad] = (bf16)(ov - (float)hi);
      }
    }
    // no barrier needed: epilogue touches no LDS; next half's first barrier syncs
  }
}

// ---------------- launch ----------------
extern "C" void kernel_launch(void* const* d_in, const int* in_sizes, int n_in,
                              void* d_out, int out_size, void* d_ws, size_t ws_size,
                              hipStream_t stream) {
  const float* x  = (const float*)d_in[0];
  const float* Wq = (const float*)d_in[1];
  const float* Wk = (const float*)d_in[2];
  const float* Wv = (const float*)d_in[3];
  const float* Wo = (const float*)d_in[4];
  const float* bo = (const float*)d_in[5];
  const float* W1 = (const float*)d_in[6];
  const float* b1 = (const float*)d_in[7];
  const float* W2 = (const float*)d_in[8];
  const float* b2 = (const float*)d_in[9];
  const float* g1 = (const float*)d_in[10];
  const float* s1 = (const float*)d_in[11];
  const float* g2 = (const float*)d_in[12];
  const float* s2 = (const float*)d_in[13];
  float* out = (float*)d_out;

  if (ws_size < 150994944ULL) return; // need 144 MB

  char* ws = (char*)d_ws;
  // weights (48 MB)
  bf16* wqkvT_hi = (bf16*)(ws + 0);
  bf16* wqkvT_lo = (bf16*)(ws + 6291456);
  bf16* woT_hi   = (bf16*)(ws + 12582912);
  bf16* woT_lo   = (bf16*)(ws + 14680064);
  bf16* w1T_hi   = (bf16*)(ws + 16777216);
  bf16* w1T_lo   = (bf16*)(ws + 25165824);
  bf16* w2T_hi   = (bf16*)(ws + 33554432);
  bf16* w2T_lo   = (bf16*)(ws + 41943040);
  // region A (64 MB): h, q, k, vT  -> later a1
  char* rA = ws + 50331648;
  bf16* h_hi  = (bf16*)(rA + 0);
  bf16* h_lo  = (bf16*)(rA + 8388608);
  bf16* q_hi  = (bf16*)(rA + 16777216); // q_lo at +AE, k_hi at +2AE, vT_hi at +4AE (EP0 offsets)
  bf16* q_lo  = (bf16*)(rA + 25165824);
  bf16* k_hi  = (bf16*)(rA + 33554432);
  bf16* vT_hi = (bf16*)(rA + 50331648);
  bf16* a1_hi = (bf16*)(rA + 0);        // 32 MB, reuses region A after attention
  bf16* a1_lo = (bf16*)(rA + 33554432);
  // region B (16 MB): ctx -> later h2
  char* rB = ws + 117440512;
  bf16* ctx_hi = (bf16*)(rB + 0);
  bf16* ctx_lo = (bf16*)(rB + 8388608);
  bf16* h2_hi  = (bf16*)(rB + 0);
  bf16* h2_lo  = (bf16*)(rB + 8388608);
  // region C (16 MB): x1 fp32
  float* x1 = (float*)(ws + 134217728);

  // 1) weight transforms
  transpose_split_kernel<<<dim3(16, 16), 256, 0, stream>>>(Wq, wqkvT_hi, wqkvT_lo, 1024, 1024);
  transpose_split_kernel<<<dim3(16, 16), 256, 0, stream>>>(Wk, wqkvT_hi + 1024 * 1024, wqkvT_lo + 1024 * 1024, 1024, 1024);
  transpose_split_kernel<<<dim3(16, 16), 256, 0, stream>>>(Wv, wqkvT_hi + 2048 * 1024, wqkvT_lo + 2048 * 1024, 1024, 1024);
  transpose_split_kernel<<<dim3(16, 16), 256, 0, stream>>>(Wo, woT_hi, woT_lo, 1024, 1024);
  transpose_split_kernel<<<dim3(64, 16), 256, 0, stream>>>(W1, w1T_hi, w1T_lo, 1024, 4096);
  transpose_split_kernel<<<dim3(16, 64), 256, 0, stream>>>(W2, w2T_hi, w2T_lo, 4096, 1024);

  // 2) LN1
  ln_split_kernel<<<4096, 256, 0, stream>>>(x, g1, s1, h_hi, h_lo);

  // 3) fused QKV GEMM (N = 3072)
  gemm_kernel<0><<<dim3(24, 64), 256, 0, stream>>>(h_hi, h_lo, wqkvT_hi, wqkvT_lo,
                                                   1024, 3072, q_hi, nullptr, nullptr, nullptr, nullptr);
  // 4) attention (paired q-tiles: uniform work per block)
  attn_kernel<<<dim3(16, 32), 256, 0, stream>>>(q_hi, q_lo, k_hi, vT_hi, ctx_hi, ctx_lo);

  // 5) Wo projection + bias + residual -> x1
  gemm_kernel<1><<<dim3(8, 64), 256, 0, stream>>>(ctx_hi, ctx_lo, woT_hi, woT_lo,
                                                  1024, 1024, nullptr, nullptr, x1, bo, x);
  // 6) LN2
  ln_split_kernel<<<4096, 256, 0, stream>>>(x1, g2, s2, h2_hi, h2_lo);

  // 7) FFN up + GELU -> a1
  gemm_kernel<2><<<dim3(32, 64), 256, 0, stream>>>(h2_hi, h2_lo, w1T_hi, w1T_lo,
                                                   1024, 4096, a1_hi, a1_lo, nullptr, b1, nullptr);
  // 8) FFN down + bias + residual -> out
  gemm_kernel<1><<<dim3(8, 64), 256, 0, stream>>>(a1_hi, a1_lo, w2T_hi, w2T_lo,
                                                  4096, 1024, nullptr, nullptr, out, b2, x1);
}

// Round 5
// 485.732 us; speedup vs baseline: 1.7316x; 1.1582x over previous
//
#include <hip/hip_runtime.h>
#include <hip/hip_bf16.h>
#include <math.h>

typedef __bf16 bf16;
typedef __bf16 bf16x4 __attribute__((ext_vector_type(4)));
typedef __bf16 bf16x8 __attribute__((ext_vector_type(8)));
typedef float f32x4 __attribute__((ext_vector_type(4)));

#define DEV static __device__ __forceinline__

constexpr int Dm = 1024;   // model dim
constexpr int Sq = 2048;   // seq len
constexpr int Mrows = 4096; // B*S
constexpr size_t AE = (size_t)Mrows * Dm; // elems per activation array

DEV void gload_lds16(const void* g, void* l) {
  __builtin_amdgcn_global_load_lds((const __attribute__((address_space(1))) unsigned int*)g,
                                   (__attribute__((address_space(3))) unsigned int*)l,
                                   16, 0, 0);
}

DEV float gelu_f(float u) {
  const float c = 0.7978845608028654f; // sqrt(2/pi)
  float t = c * (u + 0.044715f * u * u * u);
  // 0.5*(1+tanh(t)) == sigmoid(2t)
  return u / (1.0f + __expf(-2.0f * t));
}

// ---------------- weight transpose + hi split: W[K][N] -> T[N][K] (bf16 hi only) ----------------
__global__ void transpose_split_kernel(const float* __restrict__ W,
                                       bf16* __restrict__ Thi,
                                       int K, int N) {
  __shared__ float tile[64][65];
  const int t = threadIdx.x;
  const int nt = blockIdx.x * 64, kt = blockIdx.y * 64;
  #pragma unroll
  for (int i = 0; i < 16; ++i) {
    int id = i * 256 + t;
    int r = id >> 6, c = id & 63;
    tile[r][c] = W[(size_t)(kt + r) * N + nt + c];
  }
  __syncthreads();
  #pragma unroll
  for (int i = 0; i < 16; ++i) {
    int id = i * 256 + t;
    int n = id >> 6, k = id & 63;
    Thi[(size_t)(nt + n) * K + kt + k] = (bf16)tile[k][n];
  }
}

// ---------------- LayerNorm + hi/lo split (one block per row of 1024) ----------------
__global__ void ln_split_kernel(const float* __restrict__ x,
                                const float* __restrict__ gamma, const float* __restrict__ beta,
                                bf16* __restrict__ ohi, bf16* __restrict__ olo) {
  const int row = blockIdx.x, t = threadIdx.x;
  const float4 v = ((const float4*)(x + (size_t)row * Dm))[t];
  float s = v.x + v.y + v.z + v.w;
  float sq = v.x * v.x + v.y * v.y + v.z * v.z + v.w * v.w;
  #pragma unroll
  for (int off = 1; off < 64; off <<= 1) {
    s += __shfl_xor(s, off);
    sq += __shfl_xor(sq, off);
  }
  __shared__ float red[8];
  const int wave = t >> 6, lane = t & 63;
  if (lane == 0) { red[wave] = s; red[4 + wave] = sq; }
  __syncthreads();
  s = red[0] + red[1] + red[2] + red[3];
  sq = red[4] + red[5] + red[6] + red[7];
  const float mean = s * (1.0f / 1024.0f);
  const float var = sq * (1.0f / 1024.0f) - mean * mean;
  const float inv = 1.0f / sqrtf(var + 1e-5f);
  const float4 g4 = ((const float4*)gamma)[t];
  const float4 b4 = ((const float4*)beta)[t];
  float y[4];
  y[0] = (v.x - mean) * inv * g4.x + b4.x;
  y[1] = (v.y - mean) * inv * g4.y + b4.y;
  y[2] = (v.z - mean) * inv * g4.z + b4.z;
  y[3] = (v.w - mean) * inv * g4.w + b4.w;
  bf16x4 hv, lv;
  #pragma unroll
  for (int i = 0; i < 4; ++i) {
    bf16 hi = (bf16)y[i];
    hv[i] = hi;
    lv[i] = (bf16)(y[i] - (float)hi);
  }
  ((bf16x4*)(ohi + (size_t)row * Dm))[t] = hv;
  ((bf16x4*)(olo + (size_t)row * Dm))[t] = lv;
}

// ---------------- split-bf16 GEMM: C = (Ahi+Alo) @ Bhi^T(stored [N][K]) ----------------
// kt-outer: stage Ahi/Alo/Bhi once, 2 MFMA passes (hh, lh). Tile 64x128, 4 waves (2x2).
// XCD-swizzled block ids. EP: 0 = QKV epilogue, 1 = bias+residual fp32, 2 = gelu+split.
template<int EP>
__global__ __launch_bounds__(256, 4) void gemm_kernel(
    const bf16* __restrict__ Ahi, const bf16* __restrict__ Alo,
    const bf16* __restrict__ Bthi,
    int K, int N,
    bf16* __restrict__ Ohi, bf16* __restrict__ Olo,
    float* __restrict__ Of,
    const float* __restrict__ bias, const float* __restrict__ resid) {
  const int t = threadIdx.x, wave = t >> 6, lane = t & 63;
  const int wr = wave >> 1, wc = wave & 1;
  const int l15 = lane & 15, l4 = lane >> 4;
  // bijective XCD swizzle (nwg % 8 == 0 for all launches)
  const int nwg = gridDim.x * gridDim.y;
  const int p0 = blockIdx.y * gridDim.x + blockIdx.x;
  const int swz = (p0 & 7) * (nwg >> 3) + (p0 >> 3);
  const int row0 = (swz / gridDim.x) * 64, col0 = (swz % gridDim.x) * 128;

  __shared__ __align__(16) bf16 sAh[64 * 64], sAl[64 * 64];
  __shared__ __align__(16) bf16 sBh[128 * 64];

  f32x4 acc[2][4];
  #pragma unroll
  for (int m = 0; m < 2; ++m)
    #pragma unroll
    for (int n = 0; n < 4; ++n)
      acc[m][n] = (f32x4){0.f, 0.f, 0.f, 0.f};

  for (int kt = 0; kt < K; kt += 64) {
    // stage A hi/lo [64][64] and B hi [128][64]; global chunk pre-swizzled, LDS linear
    #pragma unroll
    for (int p = 0; p < 2; ++p) {
      int id = p * 256 + t;
      int r = id >> 3, c = id & 7;
      int cs = (c ^ (r & 7)) << 3;
      size_t ga = (size_t)(row0 + r) * K + kt + cs;
      gload_lds16(Ahi + ga, (char*)sAh + (p * 256 + wave * 64) * 16);
      gload_lds16(Alo + ga, (char*)sAl + (p * 256 + wave * 64) * 16);
    }
    #pragma unroll
    for (int p = 0; p < 4; ++p) {
      int id = p * 256 + t;
      int r = id >> 3, c = id & 7;
      int cs = (c ^ (r & 7)) << 3;
      gload_lds16(Bthi + (size_t)(col0 + r) * K + kt + cs,
                  (char*)sBh + (p * 256 + wave * 64) * 16);
    }
    __syncthreads();

    bf16x8 afh[2][2], afl[2][2], bfh[4][2];
    #pragma unroll
    for (int m = 0; m < 2; ++m)
      #pragma unroll
      for (int ks = 0; ks < 2; ++ks) {
        int r = wr * 32 + m * 16 + l15;
        int ch = ((ks * 4 + l4) ^ (r & 7)) << 3;
        afh[m][ks] = *(const bf16x8*)&sAh[r * 64 + ch];
        afl[m][ks] = *(const bf16x8*)&sAl[r * 64 + ch];
      }
    #pragma unroll
    for (int n = 0; n < 4; ++n)
      #pragma unroll
      for (int ks = 0; ks < 2; ++ks) {
        int r = wc * 64 + n * 16 + l15;
        int ch = ((ks * 4 + l4) ^ (r & 7)) << 3;
        bfh[n][ks] = *(const bf16x8*)&sBh[r * 64 + ch];
      }
    #pragma unroll
    for (int ks = 0; ks < 2; ++ks)
      #pragma unroll
      for (int m = 0; m < 2; ++m)
        #pragma unroll
        for (int n = 0; n < 4; ++n)
          acc[m][n] = __builtin_amdgcn_mfma_f32_16x16x32_bf16(afh[m][ks], bfh[n][ks], acc[m][n], 0, 0, 0);
    #pragma unroll
    for (int ks = 0; ks < 2; ++ks)
      #pragma unroll
      for (int m = 0; m < 2; ++m)
        #pragma unroll
        for (int n = 0; n < 4; ++n)
          acc[m][n] = __builtin_amdgcn_mfma_f32_16x16x32_bf16(afl[m][ks], bfh[n][ks], acc[m][n], 0, 0, 0);
    __syncthreads();
  }

  // epilogue
  #pragma unroll
  for (int m = 0; m < 2; ++m)
    #pragma unroll
    for (int n = 0; n < 4; ++n)
      #pragma unroll
      for (int rr = 0; rr < 4; ++rr) {
        int row = row0 + wr * 32 + m * 16 + l4 * 4 + rr;
        int col = col0 + wc * 64 + n * 16 + l15;
        float v = acc[m][n][rr];
        if constexpr (EP == 0) {
          int which = col >> 10;
          int c = col & 1023;
          if (which == 0) {
            float q = v * 0.18033688011111793f;  // 0.125 * log2(e) pre-folded into Q
            bf16 hi = (bf16)q;
            size_t ad = (size_t)row * Dm + c;
            Ohi[ad] = hi; Ohi[AE + ad] = (bf16)(q - (float)hi);  // q hi/lo
          } else if (which == 1) {
            size_t ad = (size_t)row * Dm + c;
            Ohi[2 * AE + ad] = (bf16)v;                          // k hi only
          } else {
            size_t ad = ((size_t)(row >> 11) * Dm + c) * Sq + (row & (Sq - 1));
            Ohi[4 * AE + ad] = (bf16)v;                          // v transposed hi only
          }
        } else if constexpr (EP == 1) {
          size_t ad = (size_t)row * N + col;
          Of[ad] = v + bias[col] + resid[ad];
        } else {
          float u = gelu_f(v + bias[col]);
          bf16 hi = (bf16)u;
          size_t ad = (size_t)row * N + col;
          Ohi[ad] = hi;
          Olo[ad] = (bf16)(u - (float)hi);
        }
      }
}

// ---------------- causal flash attention, double-buffered K/V, Q-split x bf16 K/V ----------------
// grid: (16, B*H), XCD-swizzled so each XCD owns 4 whole heads (K/V L2-resident).
// Each block does q-tiles {31-bx, bx} -> uniform 33 KV-iterations. 4 waves, 16 q-rows each.
__global__ __launch_bounds__(256, 4) void attn_kernel(
    const bf16* __restrict__ qhi, const bf16* __restrict__ qlo,
    const bf16* __restrict__ khi, const bf16* __restrict__ vthi,
    bf16* __restrict__ chi, bf16* __restrict__ clo) {
  const int t = threadIdx.x, wave = t >> 6, lane = t & 63;
  const int l15 = lane & 15, l4 = lane >> 4;
  // swizzle: nwg = 512, chunk/XCD = 64 = 4 heads
  const int p0 = blockIdx.y * 16 + blockIdx.x;
  const int swz = (p0 & 7) * 64 + (p0 >> 3);
  const int bx = swz & 15, bh = swz >> 4;
  const int b = bh >> 4, h = bh & 15;

  __shared__ __align__(16) bf16 sK[2][4096], sV[2][4096], sP[4096];

  for (int half = 0; half < 2; ++half) {
    const int qt = (half == 0) ? (31 - bx) : bx;
    const int qb = qt * 64;
    const int q0 = qb + wave * 16;

    // hoist Q fragments (hi and lo); Q is pre-scaled by 0.125*log2e
    bf16x8 qfh[2], qfl[2];
    #pragma unroll
    for (int ks = 0; ks < 2; ++ks) {
      size_t ad = (size_t)(b * Sq + q0 + l15) * Dm + h * 64 + ks * 32 + l4 * 8;
      qfh[ks] = *(const bf16x8*)&qhi[ad];
      qfl[ks] = *(const bf16x8*)&qlo[ad];
    }

    f32x4 cacc[4];
    float mrun[4], lrun[4];
    #pragma unroll
    for (int nd = 0; nd < 4; ++nd) cacc[nd] = (f32x4){0.f, 0.f, 0.f, 0.f};
    #pragma unroll
    for (int rr = 0; rr < 4; ++rr) { mrun[rr] = -3e38f; lrun[rr] = 0.f; }

    auto STAGE = [&](int bb, int kb) {
      #pragma unroll
      for (int p = 0; p < 2; ++p) {
        int id = p * 256 + t;
        int r = id >> 3, c = id & 7;
        int cc = (c ^ (r & 7)) << 3;
        size_t ka = (size_t)(b * Sq + kb + r) * Dm + h * 64 + cc;
        size_t va = (size_t)(b * Dm + h * 64 + r) * Sq + kb + cc;
        gload_lds16(&khi[ka], (char*)&sK[bb][0] + (p * 256 + wave * 64) * 16);
        gload_lds16(&vthi[va], (char*)&sV[bb][0] + (p * 256 + wave * 64) * 16);
      }
    };

    // prologue: stage first tile
    STAGE(0, 0);
    __syncthreads();
    int cur = 0;

    for (int kb = 0; kb <= qb; kb += 64) {
      // issue next tile's staging early (hides HBM/L2 latency under compute)
      if (kb + 64 <= qb) STAGE(cur ^ 1, kb + 64);

      // ---------- S = Q K^T (q_hi + q_lo passes) ----------
      f32x4 sacc[4];
      #pragma unroll
      for (int nk = 0; nk < 4; ++nk) sacc[nk] = (f32x4){0.f, 0.f, 0.f, 0.f};
      {
        bf16x8 kf[4][2];
        #pragma unroll
        for (int nk = 0; nk < 4; ++nk)
          #pragma unroll
          for (int ks = 0; ks < 2; ++ks) {
            int r = nk * 16 + l15;
            int ch = ((ks * 4 + l4) ^ (r & 7)) << 3;
            kf[nk][ks] = *(const bf16x8*)&sK[cur][r * 64 + ch];
          }
        #pragma unroll
        for (int ks = 0; ks < 2; ++ks)
          #pragma unroll
          for (int nk = 0; nk < 4; ++nk)
            sacc[nk] = __builtin_amdgcn_mfma_f32_16x16x32_bf16(qfh[ks], kf[nk][ks], sacc[nk], 0, 0, 0);
        #pragma unroll
        for (int ks = 0; ks < 2; ++ks)
          #pragma unroll
          for (int nk = 0; nk < 4; ++nk)
            sacc[nk] = __builtin_amdgcn_mfma_f32_16x16x32_bf16(qfl[ks], kf[nk][ks], sacc[nk], 0, 0, 0);
      }

      // ---------- causal mask (diagonal block only), online softmax in log2 domain ----------
      const bool diag = (kb == qb);
      #pragma unroll
      for (int rr = 0; rr < 4; ++rr) {
        float mx = -3e38f;
        #pragma unroll
        for (int nk = 0; nk < 4; ++nk) {
          float tv = sacc[nk][rr];
          if (diag && (nk * 16 + l15 > wave * 16 + l4 * 4 + rr)) tv = -3e38f;
          sacc[nk][rr] = tv;
          mx = fmaxf(mx, tv);
        }
        mx = fmaxf(mx, __shfl_xor(mx, 1));
        mx = fmaxf(mx, __shfl_xor(mx, 2));
        mx = fmaxf(mx, __shfl_xor(mx, 4));
        mx = fmaxf(mx, __shfl_xor(mx, 8));
        float mold = mrun[rr];
        if (mx > mold + 8.0f) {        // defer-max: only rescale on big jumps
          float corr = exp2f(mold - mx);
          lrun[rr] *= corr;
          #pragma unroll
          for (int nd = 0; nd < 4; ++nd) cacc[nd][rr] *= corr;
          mrun[rr] = mx;
          mold = mx;
        }
        float rs = 0.f;
        #pragma unroll
        for (int nk = 0; nk < 4; ++nk) {
          float p = exp2f(sacc[nk][rr] - mold);
          sacc[nk][rr] = p;
          rs += p;
        }
        rs += __shfl_xor(rs, 1);
        rs += __shfl_xor(rs, 2);
        rs += __shfl_xor(rs, 4);
        rs += __shfl_xor(rs, 8);
        lrun[rr] += rs;
      }

      // ---------- write P (bf16) to swizzled LDS (wave-private rows) ----------
      #pragma unroll
      for (int nk = 0; nk < 4; ++nk)
        #pragma unroll
        for (int rr = 0; rr < 4; ++rr) {
          int row = wave * 16 + l4 * 4 + rr;
          int col = nk * 16 + l15;
          int ad = row * 64 + (((col >> 3) ^ (row & 7)) << 3) + (col & 7);
          sP[ad] = (bf16)sacc[nk][rr];
        }

      // ---------- ctx += P V ----------
      {
        bf16x8 pf[2];
        #pragma unroll
        for (int ks = 0; ks < 2; ++ks) {
          int r = wave * 16 + l15;
          int ch = ((ks * 4 + l4) ^ (r & 7)) << 3;
          pf[ks] = *(const bf16x8*)&sP[r * 64 + ch];
        }
        bf16x8 vf[2][4];
        #pragma unroll
        for (int ks = 0; ks < 2; ++ks)
          #pragma unroll
          for (int nd = 0; nd < 4; ++nd) {
            int r = nd * 16 + l15;
            int ch = ((ks * 4 + l4) ^ (r & 7)) << 3;
            vf[ks][nd] = *(const bf16x8*)&sV[cur][r * 64 + ch];
          }
        #pragma unroll
        for (int ks = 0; ks < 2; ++ks)
          #pragma unroll
          for (int nd = 0; nd < 4; ++nd)
            cacc[nd] = __builtin_amdgcn_mfma_f32_16x16x32_bf16(pf[ks], vf[ks][nd], cacc[nd], 0, 0, 0);
      }
      __syncthreads();  // drains next-tile staging (vmcnt) + guards buf reuse
      cur ^= 1;
    }

    // epilogue: ctx / l, split, store natural layout
    #pragma unroll
    for (int rr = 0; rr < 4; ++rr) {
      float rcp = 1.0f / lrun[rr];
      int qr = q0 + l4 * 4 + rr;
      #pragma unroll
      for (int nd = 0; nd < 4; ++nd) {
        float ov = cacc[nd][rr] * rcp;
        size_t ad = (size_t)(b * Sq + qr) * Dm + h * 64 + nd * 16 + l15;
        bf16 hi = (bf16)ov;
        chi[ad] = hi;
        clo[ad] = (bf16)(ov - (float)hi);
      }
    }
    // no barrier needed: epilogue touches no LDS; next half's first barrier syncs
  }
}

// ---------------- launch ----------------
extern "C" void kernel_launch(void* const* d_in, const int* in_sizes, int n_in,
                              void* d_out, int out_size, void* d_ws, size_t ws_size,
                              hipStream_t stream) {
  const float* x  = (const float*)d_in[0];
  const float* Wq = (const float*)d_in[1];
  const float* Wk = (const float*)d_in[2];
  const float* Wv = (const float*)d_in[3];
  const float* Wo = (const float*)d_in[4];
  const float* bo = (const float*)d_in[5];
  const float* W1 = (const float*)d_in[6];
  const float* b1 = (const float*)d_in[7];
  const float* W2 = (const float*)d_in[8];
  const float* b2 = (const float*)d_in[9];
  const float* g1 = (const float*)d_in[10];
  const float* s1 = (const float*)d_in[11];
  const float* g2 = (const float*)d_in[12];
  const float* s2 = (const float*)d_in[13];
  float* out = (float*)d_out;

  if (ws_size < 150994944ULL) return; // need 144 MB

  char* ws = (char*)d_ws;
  // weights (hi only, 24 MB region)
  bf16* wqkvT_hi = (bf16*)(ws + 0);
  bf16* woT_hi   = (bf16*)(ws + 12582912);
  bf16* w1T_hi   = (bf16*)(ws + 16777216);
  bf16* w2T_hi   = (bf16*)(ws + 33554432);
  // region A (64 MB): h, q, k, vT  -> later a1
  char* rA = ws + 50331648;
  bf16* h_hi  = (bf16*)(rA + 0);
  bf16* h_lo  = (bf16*)(rA + 8388608);
  bf16* q_hi  = (bf16*)(rA + 16777216); // q_lo at +AE, k_hi at +2AE, vT_hi at +4AE (EP0 offsets)
  bf16* q_lo  = (bf16*)(rA + 25165824);
  bf16* k_hi  = (bf16*)(rA + 33554432);
  bf16* vT_hi = (bf16*)(rA + 50331648);
  bf16* a1_hi = (bf16*)(rA + 0);        // 32 MB, reuses region A after attention
  bf16* a1_lo = (bf16*)(rA + 33554432);
  // region B (16 MB): ctx -> later h2
  char* rB = ws + 117440512;
  bf16* ctx_hi = (bf16*)(rB + 0);
  bf16* ctx_lo = (bf16*)(rB + 8388608);
  bf16* h2_hi  = (bf16*)(rB + 0);
  bf16* h2_lo  = (bf16*)(rB + 8388608);
  // region C (16 MB): x1 fp32
  float* x1 = (float*)(ws + 134217728);

  // 1) weight transforms (hi only)
  transpose_split_kernel<<<dim3(16, 16), 256, 0, stream>>>(Wq, wqkvT_hi, 1024, 1024);
  transpose_split_kernel<<<dim3(16, 16), 256, 0, stream>>>(Wk, wqkvT_hi + 1024 * 1024, 1024, 1024);
  transpose_split_kernel<<<dim3(16, 16), 256, 0, stream>>>(Wv, wqkvT_hi + 2048 * 1024, 1024, 1024);
  transpose_split_kernel<<<dim3(16, 16), 256, 0, stream>>>(Wo, woT_hi, 1024, 1024);
  transpose_split_kernel<<<dim3(64, 16), 256, 0, stream>>>(W1, w1T_hi, 1024, 4096);
  transpose_split_kernel<<<dim3(16, 64), 256, 0, stream>>>(W2, w2T_hi, 4096, 1024);

  // 2) LN1
  ln_split_kernel<<<4096, 256, 0, stream>>>(x, g1, s1, h_hi, h_lo);

  // 3) fused QKV GEMM (N = 3072)
  gemm_kernel<0><<<dim3(24, 64), 256, 0, stream>>>(h_hi, h_lo, wqkvT_hi,
                                                   1024, 3072, q_hi, nullptr, nullptr, nullptr, nullptr);
  // 4) attention (paired q-tiles: uniform work per block)
  attn_kernel<<<dim3(16, 32), 256, 0, stream>>>(q_hi, q_lo, k_hi, vT_hi, ctx_hi, ctx_lo);

  // 5) Wo projection + bias + residual -> x1
  gemm_kernel<1><<<dim3(8, 64), 256, 0, stream>>>(ctx_hi, ctx_lo, woT_hi,
                                                  1024, 1024, nullptr, nullptr, x1, bo, x);
  // 6) LN2
  ln_split_kernel<<<4096, 256, 0, stream>>>(x1, g2, s2, h2_hi, h2_lo);

  // 7) FFN up + GELU -> a1
  gemm_kernel<2><<<dim3(32, 64), 256, 0, stream>>>(h2_hi, h2_lo, w1T_hi,
                                                   1024, 4096, a1_hi, a1_lo, nullptr, b1, nullptr);
  // 8) FFN down + bias + residual -> out
  gemm_kernel<1><<<dim3(8, 64), 256, 0, stream>>>(a1_hi, a1_lo, w2T_hi,
                                                  4096, 1024, nullptr, nullptr, out, b2, x1);
}

// Round 6
// 408.430 us; speedup vs baseline: 2.0593x; 1.1893x over previous
//
#include <hip/hip_runtime.h>
#include <hip/hip_bf16.h>
#include <math.h>

typedef __bf16 bf16;
typedef __bf16 bf16x4 __attribute__((ext_vector_type(4)));
typedef __bf16 bf16x8 __attribute__((ext_vector_type(8)));
typedef float f32x4 __attribute__((ext_vector_type(4)));

#define DEV static __device__ __forceinline__

constexpr int Dm = 1024;   // model dim
constexpr int Sq = 2048;   // seq len
constexpr int Mrows = 4096; // B*S
constexpr size_t AE = (size_t)Mrows * Dm; // elems per activation array

DEV void gload_lds16(const void* g, void* l) {
  __builtin_amdgcn_global_load_lds((const __attribute__((address_space(1))) unsigned int*)g,
                                   (__attribute__((address_space(3))) unsigned int*)l,
                                   16, 0, 0);
}

DEV float gelu_f(float u) {
  const float c = 0.7978845608028654f; // sqrt(2/pi)
  float t = c * (u + 0.044715f * u * u * u);
  // 0.5*(1+tanh(t)) == sigmoid(2t)
  return u / (1.0f + __expf(-2.0f * t));
}

// ---------------- weight transpose: W[K][N] -> T[N][K] (bf16) ----------------
__global__ void transpose_split_kernel(const float* __restrict__ W,
                                       bf16* __restrict__ Thi,
                                       int K, int N) {
  __shared__ float tile[64][65];
  const int t = threadIdx.x;
  const int nt = blockIdx.x * 64, kt = blockIdx.y * 64;
  #pragma unroll
  for (int i = 0; i < 16; ++i) {
    int id = i * 256 + t;
    int r = id >> 6, c = id & 63;
    tile[r][c] = W[(size_t)(kt + r) * N + nt + c];
  }
  __syncthreads();
  #pragma unroll
  for (int i = 0; i < 16; ++i) {
    int id = i * 256 + t;
    int n = id >> 6, k = id & 63;
    Thi[(size_t)(nt + n) * K + kt + k] = (bf16)tile[k][n];
  }
}

// ---------------- LayerNorm -> bf16 (one block per row of 1024) ----------------
__global__ void ln_kernel(const float* __restrict__ x,
                          const float* __restrict__ gamma, const float* __restrict__ beta,
                          bf16* __restrict__ ohi) {
  const int row = blockIdx.x, t = threadIdx.x;
  const float4 v = ((const float4*)(x + (size_t)row * Dm))[t];
  float s = v.x + v.y + v.z + v.w;
  float sq = v.x * v.x + v.y * v.y + v.z * v.z + v.w * v.w;
  #pragma unroll
  for (int off = 1; off < 64; off <<= 1) {
    s += __shfl_xor(s, off);
    sq += __shfl_xor(sq, off);
  }
  __shared__ float red[8];
  const int wave = t >> 6, lane = t & 63;
  if (lane == 0) { red[wave] = s; red[4 + wave] = sq; }
  __syncthreads();
  s = red[0] + red[1] + red[2] + red[3];
  sq = red[4] + red[5] + red[6] + red[7];
  const float mean = s * (1.0f / 1024.0f);
  const float var = sq * (1.0f / 1024.0f) - mean * mean;
  const float inv = 1.0f / sqrtf(var + 1e-5f);
  const float4 g4 = ((const float4*)gamma)[t];
  const float4 b4 = ((const float4*)beta)[t];
  bf16x4 hv;
  hv[0] = (bf16)((v.x - mean) * inv * g4.x + b4.x);
  hv[1] = (bf16)((v.y - mean) * inv * g4.y + b4.y);
  hv[2] = (bf16)((v.z - mean) * inv * g4.z + b4.z);
  hv[3] = (bf16)((v.w - mean) * inv * g4.w + b4.w);
  ((bf16x4*)(ohi + (size_t)row * Dm))[t] = hv;
}

// ---------------- bf16 GEMM: C = A @ B^T(stored [N][K]) ----------------
// kt-outer, single pass. Tile 64x128, 4 waves (2x2), 24KB LDS -> 6 blocks/CU.
// XCD-swizzled block ids. EP: 0 = QKV epilogue, 1 = bias+residual fp32, 2 = gelu.
template<int EP>
__global__ __launch_bounds__(256, 6) void gemm_kernel(
    const bf16* __restrict__ Ahi,
    const bf16* __restrict__ Bthi,
    int K, int N,
    bf16* __restrict__ Ohi,
    float* __restrict__ Of,
    const float* __restrict__ bias, const float* __restrict__ resid) {
  const int t = threadIdx.x, wave = t >> 6, lane = t & 63;
  const int wr = wave >> 1, wc = wave & 1;
  const int l15 = lane & 15, l4 = lane >> 4;
  // bijective XCD swizzle (nwg % 8 == 0 for all launches)
  const int nwg = gridDim.x * gridDim.y;
  const int p0 = blockIdx.y * gridDim.x + blockIdx.x;
  const int swz = (p0 & 7) * (nwg >> 3) + (p0 >> 3);
  const int row0 = (swz / gridDim.x) * 64, col0 = (swz % gridDim.x) * 128;

  __shared__ __align__(16) bf16 sAh[64 * 64];
  __shared__ __align__(16) bf16 sBh[128 * 64];

  f32x4 acc[2][4];
  #pragma unroll
  for (int m = 0; m < 2; ++m)
    #pragma unroll
    for (int n = 0; n < 4; ++n)
      acc[m][n] = (f32x4){0.f, 0.f, 0.f, 0.f};

  for (int kt = 0; kt < K; kt += 64) {
    // stage A [64][64] and B [128][64]; global chunk pre-swizzled, LDS linear
    #pragma unroll
    for (int p = 0; p < 2; ++p) {
      int id = p * 256 + t;
      int r = id >> 3, c = id & 7;
      int cs = (c ^ (r & 7)) << 3;
      gload_lds16(Ahi + (size_t)(row0 + r) * K + kt + cs,
                  (char*)sAh + (p * 256 + wave * 64) * 16);
    }
    #pragma unroll
    for (int p = 0; p < 4; ++p) {
      int id = p * 256 + t;
      int r = id >> 3, c = id & 7;
      int cs = (c ^ (r & 7)) << 3;
      gload_lds16(Bthi + (size_t)(col0 + r) * K + kt + cs,
                  (char*)sBh + (p * 256 + wave * 64) * 16);
    }
    __syncthreads();

    bf16x8 afh[2][2], bfh[4][2];
    #pragma unroll
    for (int m = 0; m < 2; ++m)
      #pragma unroll
      for (int ks = 0; ks < 2; ++ks) {
        int r = wr * 32 + m * 16 + l15;
        int ch = ((ks * 4 + l4) ^ (r & 7)) << 3;
        afh[m][ks] = *(const bf16x8*)&sAh[r * 64 + ch];
      }
    #pragma unroll
    for (int n = 0; n < 4; ++n)
      #pragma unroll
      for (int ks = 0; ks < 2; ++ks) {
        int r = wc * 64 + n * 16 + l15;
        int ch = ((ks * 4 + l4) ^ (r & 7)) << 3;
        bfh[n][ks] = *(const bf16x8*)&sBh[r * 64 + ch];
      }
    #pragma unroll
    for (int ks = 0; ks < 2; ++ks)
      #pragma unroll
      for (int m = 0; m < 2; ++m)
        #pragma unroll
        for (int n = 0; n < 4; ++n)
          acc[m][n] = __builtin_amdgcn_mfma_f32_16x16x32_bf16(afh[m][ks], bfh[n][ks], acc[m][n], 0, 0, 0);
    __syncthreads();
  }

  // epilogue
  #pragma unroll
  for (int m = 0; m < 2; ++m)
    #pragma unroll
    for (int n = 0; n < 4; ++n)
      #pragma unroll
      for (int rr = 0; rr < 4; ++rr) {
        int row = row0 + wr * 32 + m * 16 + l4 * 4 + rr;
        int col = col0 + wc * 64 + n * 16 + l15;
        float v = acc[m][n][rr];
        if constexpr (EP == 0) {
          int which = col >> 10;
          int c = col & 1023;
          if (which == 0) {
            float q = v * 0.18033688011111793f;  // 0.125 * log2(e) pre-folded into Q
            bf16 hi = (bf16)q;
            size_t ad = (size_t)row * Dm + c;
            Ohi[ad] = hi; Ohi[AE + ad] = (bf16)(q - (float)hi);  // q hi/lo
          } else if (which == 1) {
            size_t ad = (size_t)row * Dm + c;
            Ohi[2 * AE + ad] = (bf16)v;                          // k
          } else {
            size_t ad = ((size_t)(row >> 11) * Dm + c) * Sq + (row & (Sq - 1));
            Ohi[4 * AE + ad] = (bf16)v;                          // v transposed [b][h*64+hd][s]
          }
        } else if constexpr (EP == 1) {
          size_t ad = (size_t)row * N + col;
          Of[ad] = v + bias[col] + resid[ad];
        } else {
          size_t ad = (size_t)row * N + col;
          Ohi[ad] = (bf16)gelu_f(v + bias[col]);
        }
      }
}

// ---------------- causal flash attention, double-buffered K/V ----------------
// grid: 1024 blocks, one 64-row q-tile each; 4 waves x 16 q-rows; all co-resident (4/CU).
// Block-id map assumes round-robin XCD + CU dispatch: CU's 4 blocks share a head
// (K/V locality) and their triangular works {31-q, q, 23-q, 8+q} sum to a constant.
__global__ __launch_bounds__(256, 4) void attn_kernel(
    const bf16* __restrict__ qhi, const bf16* __restrict__ qlo,
    const bf16* __restrict__ khi, const bf16* __restrict__ vthi,
    bf16* __restrict__ chi) {
  const int t = threadIdx.x, wave = t >> 6, lane = t & 63;
  const int l15 = lane & 15, l4 = lane >> 4;
  const int i = blockIdx.x;
  const int xcd = i & 7, j = i >> 3;   // j in [0,128) within XCD
  const int hl = j & 3, qidx = j >> 2; // 4 heads/XCD, qidx in [0,32)
  int qt;
  if (qidx < 8)       qt = 31 - qidx;
  else if (qidx < 16) qt = qidx - 8;
  else if (qidx < 24) qt = 39 - qidx;
  else                qt = qidx - 16;
  const int bh = xcd * 4 + hl;
  const int b = bh >> 4, h = bh & 15;
  const int qb = qt * 64;
  const int q0 = qb + wave * 16;

  __shared__ __align__(16) bf16 sK[2][4096], sV[2][4096], sP[4096];

  // hoist Q fragments (hi and lo); Q is pre-scaled by 0.125*log2e
  bf16x8 qfh[2], qfl[2];
  #pragma unroll
  for (int ks = 0; ks < 2; ++ks) {
    size_t ad = (size_t)(b * Sq + q0 + l15) * Dm + h * 64 + ks * 32 + l4 * 8;
    qfh[ks] = *(const bf16x8*)&qhi[ad];
    qfl[ks] = *(const bf16x8*)&qlo[ad];
  }

  f32x4 cacc[4];
  float mrun[4], lrun[4];
  #pragma unroll
  for (int nd = 0; nd < 4; ++nd) cacc[nd] = (f32x4){0.f, 0.f, 0.f, 0.f};
  #pragma unroll
  for (int rr = 0; rr < 4; ++rr) { mrun[rr] = -3e38f; lrun[rr] = 0.f; }

  auto STAGE = [&](int bb, int kb) {
    #pragma unroll
    for (int p = 0; p < 2; ++p) {
      int id = p * 256 + t;
      int r = id >> 3, c = id & 7;
      int cc = (c ^ (r & 7)) << 3;
      size_t ka = (size_t)(b * Sq + kb + r) * Dm + h * 64 + cc;
      size_t va = (size_t)(b * Dm + h * 64 + r) * Sq + kb + cc;
      gload_lds16(&khi[ka], (char*)&sK[bb][0] + (p * 256 + wave * 64) * 16);
      gload_lds16(&vthi[va], (char*)&sV[bb][0] + (p * 256 + wave * 64) * 16);
    }
  };

  // prologue: stage first tile
  STAGE(0, 0);
  __syncthreads();
  int cur = 0;

  for (int kb = 0; kb <= qb; kb += 64) {
    // issue next tile's staging early (hides HBM/L2 latency under compute)
    if (kb + 64 <= qb) STAGE(cur ^ 1, kb + 64);

    // ---------- S = Q K^T (q_hi + q_lo passes) ----------
    f32x4 sacc[4];
    #pragma unroll
    for (int nk = 0; nk < 4; ++nk) sacc[nk] = (f32x4){0.f, 0.f, 0.f, 0.f};
    {
      bf16x8 kf[4][2];
      #pragma unroll
      for (int nk = 0; nk < 4; ++nk)
        #pragma unroll
        for (int ks = 0; ks < 2; ++ks) {
          int r = nk * 16 + l15;
          int ch = ((ks * 4 + l4) ^ (r & 7)) << 3;
          kf[nk][ks] = *(const bf16x8*)&sK[cur][r * 64 + ch];
        }
      #pragma unroll
      for (int ks = 0; ks < 2; ++ks)
        #pragma unroll
        for (int nk = 0; nk < 4; ++nk)
          sacc[nk] = __builtin_amdgcn_mfma_f32_16x16x32_bf16(qfh[ks], kf[nk][ks], sacc[nk], 0, 0, 0);
      #pragma unroll
      for (int ks = 0; ks < 2; ++ks)
        #pragma unroll
        for (int nk = 0; nk < 4; ++nk)
          sacc[nk] = __builtin_amdgcn_mfma_f32_16x16x32_bf16(qfl[ks], kf[nk][ks], sacc[nk], 0, 0, 0);
    }

    // ---------- causal mask (diagonal block only), online softmax in log2 domain ----------
    const bool diag = (kb == qb);
    #pragma unroll
    for (int rr = 0; rr < 4; ++rr) {
      float mx = -3e38f;
      #pragma unroll
      for (int nk = 0; nk < 4; ++nk) {
        float tv = sacc[nk][rr];
        if (diag && (nk * 16 + l15 > wave * 16 + l4 * 4 + rr)) tv = -3e38f;
        sacc[nk][rr] = tv;
        mx = fmaxf(mx, tv);
      }
      mx = fmaxf(mx, __shfl_xor(mx, 1));
      mx = fmaxf(mx, __shfl_xor(mx, 2));
      mx = fmaxf(mx, __shfl_xor(mx, 4));
      mx = fmaxf(mx, __shfl_xor(mx, 8));
      float mold = mrun[rr];
      if (mx > mold + 8.0f) {        // defer-max: only rescale on big jumps
        float corr = exp2f(mold - mx);
        lrun[rr] *= corr;
        #pragma unroll
        for (int nd = 0; nd < 4; ++nd) cacc[nd][rr] *= corr;
        mrun[rr] = mx;
        mold = mx;
      }
      float rs = 0.f;
      #pragma unroll
      for (int nk = 0; nk < 4; ++nk) {
        float p = exp2f(sacc[nk][rr] - mold);
        sacc[nk][rr] = p;
        rs += p;
      }
      rs += __shfl_xor(rs, 1);
      rs += __shfl_xor(rs, 2);
      rs += __shfl_xor(rs, 4);
      rs += __shfl_xor(rs, 8);
      lrun[rr] += rs;
    }

    // ---------- write P (bf16) to swizzled LDS (wave-private rows) ----------
    #pragma unroll
    for (int nk = 0; nk < 4; ++nk)
      #pragma unroll
      for (int rr = 0; rr < 4; ++rr) {
        int row = wave * 16 + l4 * 4 + rr;
        int col = nk * 16 + l15;
        int ad = row * 64 + (((col >> 3) ^ (row & 7)) << 3) + (col & 7);
        sP[ad] = (bf16)sacc[nk][rr];
      }

    // ---------- ctx += P V ----------
    {
      bf16x8 pf[2];
      #pragma unroll
      for (int ks = 0; ks < 2; ++ks) {
        int r = wave * 16 + l15;
        int ch = ((ks * 4 + l4) ^ (r & 7)) << 3;
        pf[ks] = *(const bf16x8*)&sP[r * 64 + ch];
      }
      bf16x8 vf[2][4];
      #pragma unroll
      for (int ks = 0; ks < 2; ++ks)
        #pragma unroll
        for (int nd = 0; nd < 4; ++nd) {
          int r = nd * 16 + l15;
          int ch = ((ks * 4 + l4) ^ (r & 7)) << 3;
          vf[ks][nd] = *(const bf16x8*)&sV[cur][r * 64 + ch];
        }
      #pragma unroll
      for (int ks = 0; ks < 2; ++ks)
        #pragma unroll
        for (int nd = 0; nd < 4; ++nd)
          cacc[nd] = __builtin_amdgcn_mfma_f32_16x16x32_bf16(pf[ks], vf[ks][nd], cacc[nd], 0, 0, 0);
    }
    __syncthreads();  // drains next-tile staging (vmcnt) + guards buf reuse
    cur ^= 1;
  }

  // epilogue: ctx / l, store natural layout (bf16)
  #pragma unroll
  for (int rr = 0; rr < 4; ++rr) {
    float rcp = 1.0f / lrun[rr];
    int qr = q0 + l4 * 4 + rr;
    #pragma unroll
    for (int nd = 0; nd < 4; ++nd) {
      float ov = cacc[nd][rr] * rcp;
      size_t ad = (size_t)(b * Sq + qr) * Dm + h * 64 + nd * 16 + l15;
      chi[ad] = (bf16)ov;
    }
  }
}

// ---------------- launch ----------------
extern "C" void kernel_launch(void* const* d_in, const int* in_sizes, int n_in,
                              void* d_out, int out_size, void* d_ws, size_t ws_size,
                              hipStream_t stream) {
  const float* x  = (const float*)d_in[0];
  const float* Wq = (const float*)d_in[1];
  const float* Wk = (const float*)d_in[2];
  const float* Wv = (const float*)d_in[3];
  const float* Wo = (const float*)d_in[4];
  const float* bo = (const float*)d_in[5];
  const float* W1 = (const float*)d_in[6];
  const float* b1 = (const float*)d_in[7];
  const float* W2 = (const float*)d_in[8];
  const float* b2 = (const float*)d_in[9];
  const float* g1 = (const float*)d_in[10];
  const float* s1 = (const float*)d_in[11];
  const float* g2 = (const float*)d_in[12];
  const float* s2 = (const float*)d_in[13];
  float* out = (float*)d_out;

  if (ws_size < 150994944ULL) return; // need 144 MB

  char* ws = (char*)d_ws;
  // weights (bf16, transposed)
  bf16* wqkvT_hi = (bf16*)(ws + 0);
  bf16* woT_hi   = (bf16*)(ws + 12582912);
  bf16* w1T_hi   = (bf16*)(ws + 16777216);
  bf16* w2T_hi   = (bf16*)(ws + 33554432);
  // region A (64 MB): h, q(hi/lo), k, vT  -> later a1
  char* rA = ws + 50331648;
  bf16* h_hi  = (bf16*)(rA + 0);
  bf16* q_hi  = (bf16*)(rA + 16777216); // q_lo at +AE, k at +2AE, vT at +4AE (EP0 offsets)
  bf16* q_lo  = (bf16*)(rA + 25165824);
  bf16* k_hi  = (bf16*)(rA + 33554432);
  bf16* vT_hi = (bf16*)(rA + 50331648);
  bf16* a1_hi = (bf16*)(rA + 0);        // 32 MB, reuses region A after attention
  // region B (16 MB): ctx -> later h2
  char* rB = ws + 117440512;
  bf16* ctx_hi = (bf16*)(rB + 0);
  bf16* h2_hi  = (bf16*)(rB + 0);       // LN2 overwrites ctx after Wo consumed it
  // region C (16 MB): x1 fp32
  float* x1 = (float*)(ws + 134217728);

  // 1) weight transforms
  transpose_split_kernel<<<dim3(16, 16), 256, 0, stream>>>(Wq, wqkvT_hi, 1024, 1024);
  transpose_split_kernel<<<dim3(16, 16), 256, 0, stream>>>(Wk, wqkvT_hi + 1024 * 1024, 1024, 1024);
  transpose_split_kernel<<<dim3(16, 16), 256, 0, stream>>>(Wv, wqkvT_hi + 2048 * 1024, 1024, 1024);
  transpose_split_kernel<<<dim3(16, 16), 256, 0, stream>>>(Wo, woT_hi, 1024, 1024);
  transpose_split_kernel<<<dim3(64, 16), 256, 0, stream>>>(W1, w1T_hi, 1024, 4096);
  transpose_split_kernel<<<dim3(16, 64), 256, 0, stream>>>(W2, w2T_hi, 4096, 1024);

  // 2) LN1
  ln_kernel<<<4096, 256, 0, stream>>>(x, g1, s1, h_hi);

  // 3) fused QKV GEMM (N = 3072)
  gemm_kernel<0><<<dim3(24, 64), 256, 0, stream>>>(h_hi, wqkvT_hi,
                                                   1024, 3072, q_hi, nullptr, nullptr, nullptr);
  // 4) attention (1024 balanced blocks, all co-resident)
  attn_kernel<<<dim3(1024), 256, 0, stream>>>(q_hi, q_lo, k_hi, vT_hi, ctx_hi);

  // 5) Wo projection + bias + residual -> x1
  gemm_kernel<1><<<dim3(8, 64), 256, 0, stream>>>(ctx_hi, woT_hi,
                                                  1024, 1024, nullptr, x1, bo, x);
  // 6) LN2
  ln_kernel<<<4096, 256, 0, stream>>>(x1, g2, s2, h2_hi);

  // 7) FFN up + GELU -> a1
  gemm_kernel<2><<<dim3(32, 64), 256, 0, stream>>>(h2_hi, w1T_hi,
                                                   1024, 4096, a1_hi, nullptr, b1, nullptr);
  // 8) FFN down + bias + residual -> out
  gemm_kernel<1><<<dim3(8, 64), 256, 0, stream>>>(a1_hi, w2T_hi,
                                                  4096, 1024, nullptr, out, b2, x1);
}